// Round 5
// baseline (1049.636 us; speedup 1.0000x reference)
//
#include <hip/hip_runtime.h>

typedef unsigned short u16;
typedef __bf16 bf16x8 __attribute__((ext_vector_type(8)));
typedef u16 u16x8 __attribute__((ext_vector_type(8)));
typedef u16 u16x4 __attribute__((ext_vector_type(4)));
typedef float f32x4 __attribute__((ext_vector_type(4)));

__device__ __forceinline__ float bf2f(u16 v) {
    union { unsigned u; float f; } c; c.u = ((unsigned)v) << 16; return c.f;
}
__device__ __forceinline__ u16 f2bf(float f) {
    union { float f; unsigned u; } c; c.f = f;
    unsigned u = c.u;
    unsigned r = (u + 0x7fffu + ((u >> 16) & 1u)) >> 16;
    return (u16)r;
}
// HW RNE f32->bf16 (single v_cvt, same rounding as f2bf; scan hot paths only)
__device__ __forceinline__ u16 f2bf_h(float f) {
    __bf16 h = (__bf16)f;
    union { __bf16 h; u16 u; } c; c.h = h; return c.u;
}

// MFMA fragment load (works for LDS or global pointers): LEFT operand from
// [m][k] row-major, or RIGHT operand from [n][k] row-major.
// row = row0 + (lane&15), k = k0 + (lane>>4)*8 .. +8.
__device__ __forceinline__ bf16x8 ldfrag(const u16* base, int stride, int row0, int k0, int lane) {
    return *(const bf16x8*)(base + (size_t)(row0 + (lane & 15)) * stride + k0 + (lane >> 4) * 8);
}

// Raw workgroup barrier: commits LDS (lgkmcnt only) but does NOT drain vmcnt,
// so cross-chunk global prefetches stay in flight (counted-vmcnt pattern).
__device__ __forceinline__ void block_barrier() {
    __builtin_amdgcn_sched_barrier(0);
    asm volatile("s_waitcnt lgkmcnt(0)");
    __builtin_amdgcn_s_barrier();
    __builtin_amdgcn_sched_barrier(0);
}

// async global->LDS, 16 B per lane. LDS dest must be wave-uniform base;
// HW writes base + lane*16.
__device__ __forceinline__ void gl2lds16(const void* g, void* l) {
    __builtin_amdgcn_global_load_lds(
        (const __attribute__((address_space(1))) unsigned int*)g,
        (__attribute__((address_space(3))) unsigned int*)l, 16, 0, 0);
}

// ---------------------------------------------------------------------------
// Weight transpose + cvt: src fp32 [1024,1024] (k,n) -> dst bf16 (n,k)
// ---------------------------------------------------------------------------
__global__ __launch_bounds__(256) void transpose_kernel(const float* __restrict__ src,
                                                        u16* __restrict__ dst) {
    __shared__ float tile[32][33];
    const int n0 = blockIdx.x * 32, k0 = blockIdx.y * 32;
    const int tx = threadIdx.x, ty = threadIdx.y;   // 32 x 8
#pragma unroll
    for (int i = 0; i < 32; i += 8)
        tile[ty + i][tx] = src[(long)(k0 + ty + i) * 1024 + n0 + tx];
    __syncthreads();
#pragma unroll
    for (int i = 0; i < 32; i += 8)
        dst[(long)(n0 + ty + i) * 1024 + k0 + tx] = f2bf(tile[tx][ty + i]);
}

// ---------------------------------------------------------------------------
// MFMA GEMM: C[M,N] = A[M,K](bf16) * BT[N,K](bf16)^T, fp32 accum.
// R5: A and B staged via global_load_lds (linear [128][32] LDS, no VGPR hop).
// ---------------------------------------------------------------------------
template <int F32OUT>
__global__ __launch_bounds__(256) void gemm_kernel(const u16* __restrict__ A,
                                                   const u16* __restrict__ BT,
                                                   void* __restrict__ Cv,
                                                   int M, int N, int K, int ldc) {
    __shared__ __attribute__((aligned(16))) u16 As[128][32];
    __shared__ __attribute__((aligned(16))) u16 Bs[128][32];
    const int tid  = threadIdx.x;
    const int lane = tid & 63;
    const int wave = tid >> 6;
    const int wm   = (wave >> 1) * 64;
    const int wn   = (wave & 1) * 64;
    const long m0  = (long)blockIdx.y * 128;
    const long n0  = (long)blockIdx.x * 128;

    const f32x4 zero = {0.f, 0.f, 0.f, 0.f};
    f32x4 acc[4][4];
#pragma unroll
    for (int i = 0; i < 4; i++)
#pragma unroll
        for (int j = 0; j < 4; j++) acc[i][j] = zero;

    const int r0 = tid >> 2;          // wave w covers rows [16w,16w+16)
    const int c0 = (tid & 3) * 8;
    const u16* Ag = A + (m0 + r0) * K + c0;
    const u16* Bg = BT + (n0 + r0) * K + c0;
    u16* AsW  = &As[wave * 16][0];        // wave-uniform LDS dests
    u16* AsW2 = &As[wave * 16 + 64][0];
    u16* BsW  = &Bs[wave * 16][0];
    u16* BsW2 = &Bs[wave * 16 + 64][0];

    for (int k0 = 0; k0 < K; k0 += 32) {
        gl2lds16(Ag + k0, AsW);
        gl2lds16(Ag + (long)64 * K + k0, AsW2);
        gl2lds16(Bg + k0, BsW);
        gl2lds16(Bg + (long)64 * K + k0, BsW2);
        __syncthreads();
        const int qk = (lane >> 4) * 8;
        const int mr = lane & 15;
        bf16x8 af[4], bfr[4];
#pragma unroll
        for (int i = 0; i < 4; i++) af[i]  = *(const bf16x8*)(&As[wm + i * 16 + mr][qk]);
#pragma unroll
        for (int j = 0; j < 4; j++) bfr[j] = *(const bf16x8*)(&Bs[wn + j * 16 + mr][qk]);
#pragma unroll
        for (int i = 0; i < 4; i++)
#pragma unroll
            for (int j = 0; j < 4; j++)
                acc[i][j] = __builtin_amdgcn_mfma_f32_16x16x32_bf16(af[i], bfr[j], acc[i][j], 0, 0, 0);
        __syncthreads();
    }

    const int cr = (lane >> 4) * 4;
    const int cc = lane & 15;
#pragma unroll
    for (int i = 0; i < 4; i++) {
#pragma unroll
        for (int j = 0; j < 4; j++) {
            const long m = m0 + wm + i * 16 + cr;
            const long n = n0 + wn + j * 16 + cc;
            if (F32OUT) {
                float* C = (float*)Cv;
#pragma unroll
                for (int r = 0; r < 4; r++) C[(m + r) * ldc + n] = acc[i][j][r];
            } else {
                u16* C = (u16*)Cv;
#pragma unroll
                for (int r = 0; r < 4; r++) C[(m + r) * ldc + n] = f2bf(acc[i][j][r]);
            }
        }
    }
}

// ---------------------------------------------------------------------------
// GEMM with fp32 A (converted to bf16 at staging; padded LDS) and bf16 BT
// (staged via global_load_lds, linear [128][32]).
// ---------------------------------------------------------------------------
#define LDA 40

__global__ __launch_bounds__(256) void gemm_a32_kernel(const float* __restrict__ A,
                                                       const u16* __restrict__ BT,
                                                       u16* __restrict__ C,
                                                       int M, int N, int K, int ldc) {
    __shared__ __attribute__((aligned(16))) u16 As[128][LDA];
    __shared__ __attribute__((aligned(16))) u16 Bs[128][32];
    const int tid  = threadIdx.x;
    const int lane = tid & 63;
    const int wave = tid >> 6;
    const int wm   = (wave >> 1) * 64;
    const int wn   = (wave & 1) * 64;
    const long m0  = (long)blockIdx.y * 128;
    const long n0  = (long)blockIdx.x * 128;

    const f32x4 zero = {0.f, 0.f, 0.f, 0.f};
    f32x4 acc[4][4];
#pragma unroll
    for (int i = 0; i < 4; i++)
#pragma unroll
        for (int j = 0; j < 4; j++) acc[i][j] = zero;

    const int r0 = tid >> 2;
    const int c0 = (tid & 3) * 8;
    const float* Ag = A + (m0 + r0) * K + c0;
    const u16* Bg = BT + (n0 + r0) * K + c0;
    u16* BsW  = &Bs[wave * 16][0];
    u16* BsW2 = &Bs[wave * 16 + 64][0];

    for (int k0 = 0; k0 < K; k0 += 32) {
        gl2lds16(Bg + k0, BsW);
        gl2lds16(Bg + (long)64 * K + k0, BsW2);
        f32x4 af0 = *(const f32x4*)(Ag + k0);
        f32x4 af1 = *(const f32x4*)(Ag + k0 + 4);
        f32x4 ag0 = *(const f32x4*)(Ag + (long)64 * K + k0);
        f32x4 ag1 = *(const f32x4*)(Ag + (long)64 * K + k0 + 4);
        u16x8 a0, a1;
#pragma unroll
        for (int r = 0; r < 4; r++) {
            a0[r] = f2bf(af0[r]); a0[r + 4] = f2bf(af1[r]);
            a1[r] = f2bf(ag0[r]); a1[r + 4] = f2bf(ag1[r]);
        }
        *(u16x8*)(&As[r0][c0])      = a0;
        *(u16x8*)(&As[r0 + 64][c0]) = a1;
        __syncthreads();
        const int qk = (lane >> 4) * 8;
        const int mr = lane & 15;
        bf16x8 af[4], bfr[4];
#pragma unroll
        for (int i = 0; i < 4; i++) af[i]  = *(const bf16x8*)(&As[wm + i * 16 + mr][qk]);
#pragma unroll
        for (int j = 0; j < 4; j++) bfr[j] = *(const bf16x8*)(&Bs[wn + j * 16 + mr][qk]);
#pragma unroll
        for (int i = 0; i < 4; i++)
#pragma unroll
            for (int j = 0; j < 4; j++)
                acc[i][j] = __builtin_amdgcn_mfma_f32_16x16x32_bf16(af[i], bfr[j], acc[i][j], 0, 0, 0);
        __syncthreads();
    }

    const int cr = (lane >> 4) * 4;
    const int cc = lane & 15;
#pragma unroll
    for (int i = 0; i < 4; i++) {
#pragma unroll
        for (int j = 0; j < 4; j++) {
            const long m = m0 + wm + i * 16 + cr;
            const long n = n0 + wn + j * 16 + cc;
#pragma unroll
            for (int r = 0; r < 4; r++) C[(m + r) * ldc + n] = f2bf(acc[i][j][r]);
        }
    }
}

// ---------------------------------------------------------------------------
// Fused: in-place L2-normalize q (x 1/16) and k per head; beta & dec per head.
// R5: reads fp32 x directly (cvt_kernel removed).
// ---------------------------------------------------------------------------
__global__ __launch_bounds__(1024) void norm_beta_kernel(
    const float* __restrict__ x, u16* __restrict__ Y,
    const float* __restrict__ Wb, const float* __restrict__ Wa,
    const float* __restrict__ A_log, const float* __restrict__ dt_bias,
    float* __restrict__ beta, float* __restrict__ dec) {
    const long row = blockIdx.x;
    const int c = threadIdx.x;
    const int h = c >> 8;
    float qv = bf2f(Y[row * 3072 + c]);
    float kv = bf2f(Y[row * 3072 + 1024 + c]);
    float xv = x[row * 1024 + c];
    float vals[10];
    vals[0] = qv * qv;
    vals[1] = kv * kv;
#pragma unroll
    for (int hh = 0; hh < 4; hh++) vals[2 + hh] = xv * Wb[c * 4 + hh];
#pragma unroll
    for (int hh = 0; hh < 4; hh++) vals[6 + hh] = xv * Wa[c * 4 + hh];
#pragma unroll
    for (int i = 0; i < 10; i++)
        for (int off = 32; off; off >>= 1) vals[i] += __shfl_xor(vals[i], off, 64);

    __shared__ float wred[16][10];
    __shared__ float sQ[4], sK[4];
    const int w = c >> 6;
    if ((c & 63) == 0) {
#pragma unroll
        for (int i = 0; i < 10; i++) wred[w][i] = vals[i];
    }
    __syncthreads();
    if (c < 4) {
        float s = wred[c * 4 + 0][0] + wred[c * 4 + 1][0] + wred[c * 4 + 2][0] + wred[c * 4 + 3][0];
        sQ[c] = rsqrtf(s + 1e-6f) * 0.0625f;
    } else if (c < 8) {
        int hh = c - 4;
        float s = wred[hh * 4 + 0][1] + wred[hh * 4 + 1][1] + wred[hh * 4 + 2][1] + wred[hh * 4 + 3][1];
        sK[hh] = rsqrtf(s + 1e-6f);
    } else if (c < 12) {
        int hh = c - 8;
        float s = 0.f;
        for (int ww = 0; ww < 16; ww++) s += wred[ww][2 + hh];
        beta[row * 4 + hh] = 1.f / (1.f + expf(-s));
    } else if (c < 16) {
        int hh = c - 12;
        float s = 0.f;
        for (int ww = 0; ww < 16; ww++) s += wred[ww][6 + hh];
        float z = s + dt_bias[hh];
        float sp = (z > 0.f) ? (z + log1pf(expf(-z))) : log1pf(expf(z));
        dec[row * 4 + hh] = expf(-expf(A_log[hh]) * sp);
    }
    __syncthreads();
    Y[row * 3072 + c]        = f2bf(qv * sQ[h]);
    Y[row * 3072 + 1024 + c] = f2bf(kv * sK[h]);
}

// ---------------------------------------------------------------------------
// PASS A (chunk-parallel prep): per (bh, chunk) compute A matrix, T=(I+A)^-1
// via nilpotent doubling, and M matrix. Writes T, M (bf16 [64][64]) to global.
// Also writes the per-chunk scalar tables sfg[bh*64+c][256]:
//   [0:64)=gam  [64:128)=beta*gam  [128:192)=beta  [192:256)=ksc (gamL/gam)
// ---------------------------------------------------------------------------
__global__ __launch_bounds__(256) void prep_kernel(const u16* __restrict__ Y,
                                                   const float* __restrict__ beta,
                                                   const float* __restrict__ dec,
                                                   u16* __restrict__ Tg,
                                                   u16* __restrict__ Mg,
                                                   float* __restrict__ sfg) {
    __shared__ __attribute__((aligned(16))) u16 lds[38400];
    __shared__ float sf[320];
    u16* KS  = lds;            // 64 x 264
    u16* QS  = lds + 16896;    // 64 x 264
    u16* AM  = lds + 33792;    // 64 x 72
    // overlays (valid after G phase; KS/QS dead):
    u16* Tm  = lds;            // 64 x 72
    u16* AMT = lds + 4608;
    u16* MP  = lds + 9216;
    u16* MPT = lds + 13824;

    const int bx = blockIdx.x;
    const int bh = bx >> 6, c = bx & 63;
    const int b = bh >> 2, h = bh & 3;
    const int tid = threadIdx.x, lane = tid & 63, wv = tid >> 6;
    const int quad = lane >> 4, l15 = lane & 15;
    const int tld = tid >> 2, seg = tid & 3;
    const long bt0 = (long)b * 4096 + c * 64;
    u16* Tc = Tg + (size_t)(bh * 64 + c) * 4096;
    u16* Mc = Mg + (size_t)(bh * 64 + c) * 4096;
    const f32x4 z4 = {0.f, 0.f, 0.f, 0.f};

    // ---- stage K,Q; gamma prefix ----
    {
        const long rb = (bt0 + tld) * 3072 + h * 256 + seg * 64;
#pragma unroll
        for (int i = 0; i < 8; i++) {
            *(u16x8*)&KS[tld * 264 + seg * 64 + i * 8] = *(const u16x8*)&Y[rb + 1024 + i * 8];
            *(u16x8*)&QS[tld * 264 + seg * 64 + i * 8] = *(const u16x8*)&Y[rb + i * 8];
        }
    }
    if (wv == 0) {
        float d   = dec [(bt0 + lane) * 4 + h];
        float bt_ = beta[(bt0 + lane) * 4 + h];
        float lg = log2f(fmaxf(d, 1e-30f));
#pragma unroll
        for (int off = 1; off < 64; off <<= 1) {
            float o = __shfl_up(lg, off, 64);
            if (lane >= off) lg += o;
        }
        sf[lane] = lg; sf[192 + lane] = bt_;
        float lgL = __shfl(lg, 63, 64);
        float g = exp2f(lg);
        float* sfc = sfg + (size_t)(bh * 64 + c) * 256;
        sfc[lane]       = g;
        sfc[64 + lane]  = bt_ * g;
        sfc[128 + lane] = bt_;
        sfc[192 + lane] = exp2f(lgL - lg);
    }
    __syncthreads();   // B1

    // ---- G phase: waves 0-1 -> A matrix (LDS); waves 2-3 -> M (global) ----
    {
        const u16* Ab = (wv < 2) ? KS : QS;
        const int mb = (wv & 1) * 32;
        f32x4 g[2][4];
#pragma unroll
        for (int mi = 0; mi < 2; mi++)
#pragma unroll
            for (int sj = 0; sj < 4; sj++) g[mi][sj] = z4;
#pragma unroll 2
        for (int k0 = 0; k0 < 256; k0 += 32) {
            bf16x8 bfr[4];
#pragma unroll
            for (int sj = 0; sj < 4; sj++) bfr[sj] = ldfrag(KS, 264, sj * 16, k0, lane);
#pragma unroll
            for (int mi = 0; mi < 2; mi++) {
                bf16x8 af = ldfrag(Ab, 264, mb + mi * 16, k0, lane);
#pragma unroll
                for (int sj = 0; sj < 4; sj++)
                    g[mi][sj] = __builtin_amdgcn_mfma_f32_16x16x32_bf16(af, bfr[sj], g[mi][sj], 0, 0, 0);
            }
        }
#pragma unroll
        for (int mi = 0; mi < 2; mi++)
#pragma unroll
            for (int sj = 0; sj < 4; sj++)
#pragma unroll
                for (int r = 0; r < 4; r++) {
                    const int t_ = mb + mi * 16 + quad * 4 + r, s_ = sj * 16 + l15;
                    if (wv < 2)
                        AM[t_ * 72 + s_] = (s_ < t_) ? f2bf(sf[192 + t_] * exp2f(sf[t_] - sf[s_]) * g[mi][sj][r]) : (u16)0;
                    else
                        Mc[t_ * 64 + s_] = (s_ <= t_) ? f2bf(exp2f(sf[t_] - sf[s_]) * g[mi][sj][r]) : (u16)0;
                }
    }
    __syncthreads();   // B2 (KS/QS dead)

    // ---- solve init: T = I - A, A^T ----
    {
        const int t_ = tid >> 2;
#pragma unroll
        for (int i = 0; i < 16; i++) {
            const int s_ = (tid & 3) * 16 + i;
            const u16 a = AM[t_ * 72 + s_];
            Tm[t_ * 72 + s_] = (t_ == s_) ? (u16)0x3F80 : (u16)(a ^ 0x8000);
            AMT[s_ * 72 + t_] = a;
        }
    }
    __syncthreads();   // B3

    // ---- r1: Mp = N*N ----
    {
        f32x4 sq[4];
#pragma unroll
        for (int sj = 0; sj < 4; sj++) sq[sj] = z4;
#pragma unroll
        for (int k0 = 0; k0 < 64; k0 += 32) {
            bf16x8 a = ldfrag(AM, 72, 16 * wv, k0, lane);
#pragma unroll
            for (int sj = 0; sj < 4; sj++) {
                bf16x8 bb = ldfrag(AMT, 72, sj * 16, k0, lane);
                sq[sj] = __builtin_amdgcn_mfma_f32_16x16x32_bf16(a, bb, sq[sj], 0, 0, 0);
            }
        }
#pragma unroll
        for (int sj = 0; sj < 4; sj++)
#pragma unroll
            for (int r = 0; r < 4; r++) {
                const int t_ = 16 * wv + quad * 4 + r, s_ = sj * 16 + l15;
                const u16 vbf = f2bf(sq[sj][r]);
                MP[t_ * 72 + s_] = vbf;
                MPT[s_ * 72 + t_] = vbf;
            }
        __syncthreads();   // B4
    }

    // ---- fused rounds: T += T*Mp ; Mp <- Mp*Mp (skip on last) ----
#pragma unroll 1
    for (int jj = 0; jj < 5; jj++) {
        const bool last = (jj == 4);
        f32x4 pp[4], sq[4];
#pragma unroll
        for (int sj = 0; sj < 4; sj++) {
            sq[sj] = z4;
#pragma unroll
            for (int r = 0; r < 4; r++)
                pp[sj][r] = bf2f(Tm[(16 * wv + quad * 4 + r) * 72 + sj * 16 + l15]);
        }
#pragma unroll
        for (int k0 = 0; k0 < 64; k0 += 32) {
            bf16x8 at = ldfrag(Tm, 72, 16 * wv, k0, lane);
            bf16x8 am = ldfrag(MP, 72, 16 * wv, k0, lane);
#pragma unroll
            for (int sj = 0; sj < 4; sj++) {
                bf16x8 bb = ldfrag(MPT, 72, sj * 16, k0, lane);
                pp[sj] = __builtin_amdgcn_mfma_f32_16x16x32_bf16(at, bb, pp[sj], 0, 0, 0);
                if (!last) sq[sj] = __builtin_amdgcn_mfma_f32_16x16x32_bf16(am, bb, sq[sj], 0, 0, 0);
            }
        }
        __syncthreads();
#pragma unroll
        for (int sj = 0; sj < 4; sj++)
#pragma unroll
            for (int r = 0; r < 4; r++) {
                const int t_ = 16 * wv + quad * 4 + r, s_ = sj * 16 + l15;
                Tm[t_ * 72 + s_] = f2bf(pp[sj][r]);
                if (!last) {
                    const u16 vbf = f2bf(sq[sj][r]);
                    MP[t_ * 72 + s_] = vbf;
                    MPT[s_ * 72 + t_] = vbf;
                }
            }
        __syncthreads();
    }

    // ---- write T to global ----
    {
        const int t_ = tid >> 2;
#pragma unroll
        for (int i = 0; i < 16; i++) {
            const int s_ = (tid & 3) * 16 + i;
            Tc[t_ * 64 + s_] = Tm[t_ * 72 + s_];
        }
    }
}

// ---------------------------------------------------------------------------
// PASS B (sequential scan): grid 64 = bh(16) x dvs(4), 512 threads / 8 waves,
// ROLE-SPLIT: waves 0-3 = K-role (wq = wv&3), waves 4-7 = Q-role.
// (unchanged from R4 -- verified winner: 323 us, VGPR 116, no spill)
// ---------------------------------------------------------------------------
struct Frag { bf16x8 f[8]; };

__global__ __launch_bounds__(512, 2) void scan_kernel(const u16* __restrict__ Y,
                                                      const float* __restrict__ sfg,
                                                      const u16* __restrict__ Tg,
                                                      const u16* __restrict__ Mg,
                                                      u16* __restrict__ Ob) {
    __shared__ __attribute__((aligned(16))) u16 KT[4 * 4616];   // [dk-panel][dk6*72 + t_rot]
    __shared__ __attribute__((aligned(16))) u16 ST[64 * 264];   // [dv][dk]
    __shared__ __attribute__((aligned(16))) u16 RHST[64 * 72];  // [dv][t]
    __shared__ __attribute__((aligned(16))) u16 UTp[64 * 72];   // [dv][t] plain
    __shared__ __attribute__((aligned(16))) u16 UTk[64 * 72];   // [dv][t] ksc-folded

    const int bx = blockIdx.x;
    const int bh = bx >> 2, dvs = bx & 3;
    const int b = bh >> 2, h = bh & 3;
    const int tid = threadIdx.x, lane = tid & 63, wv = tid >> 6;
    const int wq = wv & 3;           // t-group (16 t rows)
    const int isQ = wv >> 2;         // role: 0 = K-side, 1 = Q-side
    const int quad = lane >> 4, l15 = lane & 15;
    const int tW = 16 * wq + l15;                     // lane's t (output col)
    const int tph = 16 * ((wq + quad) & 3) + l15;     // rotated t for KT writes
    int toff[4];                                      // KT read t-rotation per dk-tile
#pragma unroll
    for (int j = 0; j < 4; j++) toff[j] = ((((j << 1) + (l15 >> 3)) & 3) << 4);
    const f32x4 z4 = {0.f, 0.f, 0.f, 0.f};

    f32x4 Sacc[2][4];   // [dv-tile within role half][dk-tile within wq slice]
#pragma unroll
    for (int i = 0; i < 2; i++)
#pragma unroll
        for (int j = 0; j < 4; j++) Sacc[i][j] = z4;
    for (int i = tid; i < 64 * 264; i += 512) ST[i] = 0;
    __syncthreads();

    const long roleOff = isQ ? 0 : 1024;   // q at +0, k at +1024 in Y rows
    Frag F0, F1;
    {
        const u16* Pg = Y + ((long)b * 4096) * 3072 + roleOff + h * 256;
#pragma unroll
        for (int i = 0; i < 8; i++) F0.f[i] = ldfrag(Pg, 3072, 16 * wq, i * 32, lane);
    }

    // deferred-O carry state (Q-role only)
    f32x4 oaccP[4];
#pragma unroll
    for (int j = 0; j < 4; j++) oaccP[j] = z4;
    bf16x8 amP0 = {}, amP1 = {};
    long obP = 0;
    int havePrev = 0;

    auto body = [&](Frag& cur, Frag& nxt, int c) {
        const long bt0 = (long)b * 4096 + (long)c * 64;
        const int cn = (c < 63) ? c + 1 : 63;

        // ---- issue NEXT-chunk fragment prefetch (role's operand only) ----
        {
            const u16* Pg = Y + ((long)b * 4096 + (long)cn * 64) * 3072 + roleOff + h * 256;
#pragma unroll
            for (int i = 0; i < 8; i++) nxt.f[i] = ldfrag(Pg, 3072, 16 * wq, i * 32, lane);
        }

        // ---- current-chunk T + scalars (both roles) ----
        const u16* Tc = Tg + (size_t)(bh * 64 + c) * 4096;
        bf16x8 at0 = ldfrag(Tc, 64, 16 * wq, 0, lane);
        bf16x8 at1 = ldfrag(Tc, 64, 16 * wq, 32, lane);
        const float* sfc = sfg + (size_t)(bh * 64 + c) * 256;
        const float gam_l = sfc[tW];
        const float bg_l  = sfc[64 + tW];
        const float bet_l = sfc[128 + tW];
        const float ksc_l = sfc[192 + tW];
        const float gL    = sfc[63];

        u16x4 v4[4];
        if (!isQ) {
            // K-role: V loads (for RHS)
            const u16* Vr = Y + (bt0 + tW) * 3072 + 2048 + h * 256 + dvs * 64;
#pragma unroll
            for (int j = 0; j < 4; j++) v4[j] = *(const u16x4*)(Vr + j * 16 + quad * 4);
        } else {
            // Q-role: M loads + deferred O of previous chunk
            const u16* Mc = Mg + (size_t)(bh * 64 + c) * 4096;
            bf16x8 amN0 = ldfrag(Mc, 64, 16 * wq, 0, lane);
            bf16x8 amN1 = ldfrag(Mc, 64, 16 * wq, 32, lane);
            if (havePrev) {
#pragma unroll
                for (int sj = 0; sj < 4; sj++) {
                    bf16x8 ua0 = ldfrag(UTp, 72, sj * 16, 0, lane);
                    oaccP[sj] = __builtin_amdgcn_mfma_f32_16x16x32_bf16(ua0, amP0, oaccP[sj], 0, 0, 0);
                    bf16x8 ua1 = ldfrag(UTp, 72, sj * 16, 32, lane);
                    oaccP[sj] = __builtin_amdgcn_mfma_f32_16x16x32_bf16(ua1, amP1, oaccP[sj], 0, 0, 0);
                }
#pragma unroll
                for (int sj = 0; sj < 4; sj++) {
                    u16x4 o4;
#pragma unroll
                    for (int r = 0; r < 4; r++) o4[r] = f2bf_h(oaccP[sj][r]);
                    *(u16x4*)(Ob + obP + sj * 16 + quad * 4) = o4;
                }
            }
            amP0 = amN0; amP1 = amN1;
        }

        // ---- P phase: p = ST @ role-frag, C[dv-tile][t=wq group] ----
        f32x4 p[4];
#pragma unroll
        for (int j = 0; j < 4; j++) p[j] = z4;
#pragma unroll
        for (int i = 0; i < 8; i++) {
            bf16x8 sfr[4];
#pragma unroll
            for (int j = 0; j < 4; j++) sfr[j] = ldfrag(ST, 264, j * 16, i * 32, lane);
#pragma unroll
            for (int j = 0; j < 4; j++)
                p[j] = __builtin_amdgcn_mfma_f32_16x16x32_bf16(sfr[j], cur.f[i], p[j], 0, 0, 0);
        }

        if (!isQ) {
            // ---- KT build from cur (K frags): raw bits, rotated t ----
#pragma unroll
            for (int i = 0; i < 8; i++) {
                const u16* src = (const u16*)&cur.f[i];
                u16* dst = KT + (i >> 1) * 4616 + ((i & 1) * 32 + quad * 8) * 72 + tph;
#pragma unroll
                for (int jj = 0; jj < 8; jj++) dst[jj * 72] = src[jj];
            }
            // ---- RHS = beta*V - beta*gam*pk ----
#pragma unroll
            for (int j = 0; j < 4; j++)
#pragma unroll
                for (int r = 0; r < 4; r++) {
                    const int row = j * 16 + quad * 4 + r;
                    RHST[row * 72 + tW] = f2bf_h(bet_l * bf2f(v4[j][r]) - bg_l * p[j][r]);
                }
        } else {
            // ---- oacc = gam*pq (becomes next chunk's deferred-O base) ----
#pragma unroll
            for (int j = 0; j < 4; j++)
#pragma unroll
                for (int r = 0; r < 4; r++) oaccP[j][r] = gam_l * p[j][r];
            obP = (bt0 + tW) * 1024 + h * 256 + (long)dvs * 64;
            havePrev = 1;
        }
        block_barrier();   // B2 (RHST + KT visible)

        // ---- U phase: role K does dv tiles 0-1, role Q does 2-3 ----
        {
#pragma unroll
            for (int s2 = 0; s2 < 2; s2++) {
                const int sj = isQ * 2 + s2;
                f32x4 uu = z4;
                bf16x8 ra0 = ldfrag(RHST, 72, sj * 16, 0, lane);
                uu = __builtin_amdgcn_mfma_f32_16x16x32_bf16(ra0, at0, uu, 0, 0, 0);
                bf16x8 ra1 = ldfrag(RHST, 72, sj * 16, 32, lane);
                uu = __builtin_amdgcn_mfma_f32_16x16x32_bf16(ra1, at1, uu, 0, 0, 0);
#pragma unroll
                for (int r = 0; r < 4; r++) {
                    const int row = sj * 16 + quad * 4 + r;
                    UTp[row * 72 + tW] = f2bf_h(uu[r]);
                    UTk[row * 72 + tW] = f2bf_h(ksc_l * uu[r]);
                }
            }
        }
        block_barrier();   // B3 (UTp/UTk visible)

        // ---- S update: dv-half = role, dk slice = wq ----
        {
#pragma unroll
            for (int i = 0; i < 2; i++)
#pragma unroll
                for (int j = 0; j < 4; j++) Sacc[i][j] *= gL;
            const u16* KTp = KT + wq * 4616;
#pragma unroll
            for (int k0 = 0; k0 < 64; k0 += 32) {
                bf16x8 au[2], bk[4];
#pragma unroll
                for (int i = 0; i < 2; i++) au[i] = ldfrag(UTk, 72, isQ * 32 + i * 16, k0, lane);
#pragma unroll
                for (int j = 0; j < 4; j++)
                    bk[j] = *(const bf16x8*)(KTp + (size_t)(j * 16 + l15) * 72 +
                                             ((k0 + quad * 8 + toff[j]) & 63));
#pragma unroll
                for (int i = 0; i < 2; i++)
#pragma unroll
                    for (int j = 0; j < 4; j++)
                        Sacc[i][j] = __builtin_amdgcn_mfma_f32_16x16x32_bf16(au[i], bk[j], Sacc[i][j], 0, 0, 0);
            }
#pragma unroll
            for (int i = 0; i < 2; i++)
#pragma unroll
                for (int j = 0; j < 4; j++)
#pragma unroll
                    for (int r = 0; r < 4; r++)
                        ST[(isQ * 32 + i * 16 + quad * 4 + r) * 264 + wq * 64 + j * 16 + l15] = f2bf_h(Sacc[i][j][r]);
        }
        block_barrier();   // B4 (ST visible for next chunk)
    };

#pragma unroll 1
    for (int c = 0; c < 64; c += 2) {
        body(F0, F1, c);
        body(F1, F0, c + 1);
    }

    // ---- final deferred O (chunk 63, Q-role) ----
    if (isQ) {
#pragma unroll
        for (int sj = 0; sj < 4; sj++) {
            bf16x8 ua0 = ldfrag(UTp, 72, sj * 16, 0, lane);
            oaccP[sj] = __builtin_amdgcn_mfma_f32_16x16x32_bf16(ua0, amP0, oaccP[sj], 0, 0, 0);
            bf16x8 ua1 = ldfrag(UTp, 72, sj * 16, 32, lane);
            oaccP[sj] = __builtin_amdgcn_mfma_f32_16x16x32_bf16(ua1, amP1, oaccP[sj], 0, 0, 0);
        }
#pragma unroll
        for (int sj = 0; sj < 4; sj++) {
            u16x4 o4;
#pragma unroll
            for (int r = 0; r < 4; r++) o4[r] = f2bf_h(oaccP[sj][r]);
            *(u16x4*)(Ob + obP + sj * 16 + quad * 4) = o4;
        }
    }
}

// ---------------------------------------------------------------------------
// Gated RMSNorm + SiLU; writes og IN PLACE into G.
// ---------------------------------------------------------------------------
__global__ __launch_bounds__(256) void gate_norm_kernel(const u16* __restrict__ O,
                                                        u16* __restrict__ G,
                                                        const float* __restrict__ norm_w) {
    const long row = blockIdx.x >> 2;
    const int h = blockIdx.x & 3;
    const int dv = threadIdx.x;
    const long idx = row * 1024 + h * 256 + dv;
    float o = bf2f(O[idx]);
    float s = o * o;
#pragma unroll
    for (int off = 32; off; off >>= 1) s += __shfl_xor(s, off, 64);
    __shared__ float wsum[4];
    if ((dv & 63) == 0) wsum[dv >> 6] = s;
    __syncthreads();
    const float tot = wsum[0] + wsum[1] + wsum[2] + wsum[3];
    const float r = rsqrtf(tot * (1.f / 256.f) + 1e-5f);
    const float g = bf2f(G[idx]);
    const float val = o * r * norm_w[dv] * (g / (1.f + expf(-g)));
    G[idx] = f2bf(val);
}

// ---------------------------------------------------------------------------
extern "C" void kernel_launch(void* const* d_in, const int* in_sizes, int n_in,
                              void* d_out, int out_size, void* d_ws, size_t ws_size,
                              hipStream_t stream) {
    const float* x       = (const float*)d_in[0];
    const float* Wq      = (const float*)d_in[1];
    const float* Wk      = (const float*)d_in[2];
    const float* Wv      = (const float*)d_in[3];
    const float* Wb      = (const float*)d_in[4];
    const float* Wa      = (const float*)d_in[5];
    const float* A_log   = (const float*)d_in[6];
    const float* dt_bias = (const float*)d_in[7];
    const float* Wg      = (const float*)d_in[8];
    const float* norm_w  = (const float*)d_in[9];
    const float* Wo      = (const float*)d_in[10];

    // workspace: identical 171 MB footprint as previous rounds (proven to fit).
    char* p = (char*)d_ws;
    u16*   WT   = (u16*)p;   p += (size_t)5120 * 1024 * 2;   // WqT|WkT|WvT|WgT|WoT bf16
    u16*   Y    = (u16*)p;   p += (size_t)16384 * 3072 * 2;  // q|k|v bf16
    u16*   G    = (u16*)p;   p += (size_t)16384 * 1024 * 2;  // T|M (prep+scan), then gate/og
    u16*   XO   = (u16*)p;   p += (size_t)16384 * 1024 * 2;  // O (scan output)
    float* beta = (float*)p; p += (size_t)16384 * 4 * 4;
    float* dec  = (float*)p; p += (size_t)16384 * 4 * 4;

    u16* Tg = G;                                  // [16*64][64*64] bf16, 8.4 MB
    u16* Mg = G + (size_t)1024 * 4096;            // same, next 8.4 MB
    // sfg (1 MB) overlays WqT, which is dead after the big QKV GEMM.
    float* sfg = (float*)WT;                      // [16*64][256] f32

    dim3 tb(32, 8), tg(32, 32);
    transpose_kernel<<<tg, tb, 0, stream>>>(Wq, WT + (size_t)0 * 1024 * 1024);
    transpose_kernel<<<tg, tb, 0, stream>>>(Wk, WT + (size_t)1 * 1024 * 1024);
    transpose_kernel<<<tg, tb, 0, stream>>>(Wv, WT + (size_t)2 * 1024 * 1024);
    transpose_kernel<<<tg, tb, 0, stream>>>(Wg, WT + (size_t)3 * 1024 * 1024);
    transpose_kernel<<<tg, tb, 0, stream>>>(Wo, WT + (size_t)4 * 1024 * 1024);

    // Y = x @ [Wq|Wk|Wv]   (M=16384, N=3072, K=1024; fp32 A read directly)
    gemm_a32_kernel<<<dim3(3072 / 128, 16384 / 128), 256, 0, stream>>>(
        x, WT, Y, 16384, 3072, 1024, 3072);

    norm_beta_kernel<<<16384, 1024, 0, stream>>>(x, Y, Wb, Wa, A_log, dt_bias, beta, dec);

    // prep also writes sfg into the dead WqT region
    prep_kernel<<<1024, 256, 0, stream>>>(Y, beta, dec, Tg, Mg, sfg);

    // scan writes O into XO
    scan_kernel<<<64, 512, 0, stream>>>(Y, sfg, Tg, Mg, XO);

    // gate = x @ Wg (overwrites T/M region -> after scan)
    gemm_a32_kernel<<<dim3(1024 / 128, 16384 / 128), 256, 0, stream>>>(
        x, WT + (size_t)3072 * 1024, G, 16384, 1024, 1024, 1024);

    gate_norm_kernel<<<16384 * 4, 256, 0, stream>>>(XO, G, norm_w);

    // out = og @ Wo   (fp32 out)
    gemm_kernel<1><<<dim3(1024 / 128, 16384 / 128), 256, 0, stream>>>(
        G, WT + (size_t)4096 * 1024, d_out, 16384, 1024, 1024, 1024);
}

// Round 6
// 996.503 us; speedup vs baseline: 1.0533x; 1.0533x over previous
//
#include <hip/hip_runtime.h>

typedef unsigned short u16;
typedef __bf16 bf16x8 __attribute__((ext_vector_type(8)));
typedef u16 u16x8 __attribute__((ext_vector_type(8)));
typedef u16 u16x4 __attribute__((ext_vector_type(4)));
typedef float f32x4 __attribute__((ext_vector_type(4)));

__device__ __forceinline__ float bf2f(u16 v) {
    union { unsigned u; float f; } c; c.u = ((unsigned)v) << 16; return c.f;
}
// HW RNE f32->bf16 (single v_cvt; same rounding as the software round-to-nearest-even)
__device__ __forceinline__ u16 f2bf_h(float f) {
    __bf16 h = (__bf16)f;
    union { __bf16 h; u16 u; } c; c.h = h; return c.u;
}

// MFMA fragment load (works for LDS or global pointers): LEFT operand from
// [m][k] row-major, or RIGHT operand from [n][k] row-major.
// row = row0 + (lane&15), k = k0 + (lane>>4)*8 .. +8.
__device__ __forceinline__ bf16x8 ldfrag(const u16* base, int stride, int row0, int k0, int lane) {
    return *(const bf16x8*)(base + (size_t)(row0 + (lane & 15)) * stride + k0 + (lane >> 4) * 8);
}

// Raw workgroup barrier: commits LDS (lgkmcnt only) but does NOT drain vmcnt,
// so cross-chunk global prefetches stay in flight (counted-vmcnt pattern).
__device__ __forceinline__ void block_barrier() {
    __builtin_amdgcn_sched_barrier(0);
    asm volatile("s_waitcnt lgkmcnt(0)");
    __builtin_amdgcn_s_barrier();
    __builtin_amdgcn_sched_barrier(0);
}

// async global->LDS, 16 B per lane. LDS dest must be wave-uniform base;
// HW writes base + lane*16.
__device__ __forceinline__ void gl2lds16(const void* g, void* l) {
    __builtin_amdgcn_global_load_lds(
        (const __attribute__((address_space(1))) unsigned int*)g,
        (__attribute__((address_space(3))) unsigned int*)l, 16, 0, 0);
}

// ---------------------------------------------------------------------------
// fp32 -> bf16 elementwise convert (restored; hardware v_cvt rounding)
// ---------------------------------------------------------------------------
__global__ __launch_bounds__(256) void cvt_kernel(const float* __restrict__ src,
                                                  u16* __restrict__ dst) {
    const long i = ((long)blockIdx.x * 256 + threadIdx.x) * 4;
    f32x4 v = *(const f32x4*)(src + i);
    u16x4 o;
#pragma unroll
    for (int r = 0; r < 4; r++) o[r] = f2bf_h(v[r]);
    *(u16x4*)(dst + i) = o;
}

// ---------------------------------------------------------------------------
// Weight transpose + cvt: src fp32 [1024,1024] (k,n) -> dst bf16 (n,k)
// ---------------------------------------------------------------------------
__global__ __launch_bounds__(256) void transpose_kernel(const float* __restrict__ src,
                                                        u16* __restrict__ dst) {
    __shared__ float tile[32][33];
    const int n0 = blockIdx.x * 32, k0 = blockIdx.y * 32;
    const int tx = threadIdx.x, ty = threadIdx.y;   // 32 x 8
#pragma unroll
    for (int i = 0; i < 32; i += 8)
        tile[ty + i][tx] = src[(long)(k0 + ty + i) * 1024 + n0 + tx];
    __syncthreads();
#pragma unroll
    for (int i = 0; i < 32; i += 8)
        dst[(long)(n0 + ty + i) * 1024 + k0 + tx] = f2bf_h(tile[tx][ty + i]);
}

// ---------------------------------------------------------------------------
// MFMA GEMM: C[M,N] = A[M,K](bf16) * BT[N,K](bf16)^T, fp32 accum.
// A and B staged via global_load_lds (linear [128][32] LDS, no VGPR hop) --
// the m97 structure. Used for QKV (big) and out GEMMs.
// ---------------------------------------------------------------------------
template <int F32OUT>
__global__ __launch_bounds__(256) void gemm_kernel(const u16* __restrict__ A,
                                                   const u16* __restrict__ BT,
                                                   void* __restrict__ Cv,
                                                   int M, int N, int K, int ldc) {
    __shared__ __attribute__((aligned(16))) u16 As[128][32];
    __shared__ __attribute__((aligned(16))) u16 Bs[128][32];
    const int tid  = threadIdx.x;
    const int lane = tid & 63;
    const int wave = tid >> 6;
    const int wm   = (wave >> 1) * 64;
    const int wn   = (wave & 1) * 64;
    const long m0  = (long)blockIdx.y * 128;
    const long n0  = (long)blockIdx.x * 128;

    const f32x4 zero = {0.f, 0.f, 0.f, 0.f};
    f32x4 acc[4][4];
#pragma unroll
    for (int i = 0; i < 4; i++)
#pragma unroll
        for (int j = 0; j < 4; j++) acc[i][j] = zero;

    const int r0 = tid >> 2;          // wave w covers rows [16w,16w+16)
    const int c0 = (tid & 3) * 8;
    const u16* Ag = A + (m0 + r0) * K + c0;
    const u16* Bg = BT + (n0 + r0) * K + c0;
    u16* AsW  = &As[wave * 16][0];        // wave-uniform LDS dests
    u16* AsW2 = &As[wave * 16 + 64][0];
    u16* BsW  = &Bs[wave * 16][0];
    u16* BsW2 = &Bs[wave * 16 + 64][0];

    for (int k0 = 0; k0 < K; k0 += 32) {
        gl2lds16(Ag + k0, AsW);
        gl2lds16(Ag + (long)64 * K + k0, AsW2);
        gl2lds16(Bg + k0, BsW);
        gl2lds16(Bg + (long)64 * K + k0, BsW2);
        __syncthreads();
        const int qk = (lane >> 4) * 8;
        const int mr = lane & 15;
        bf16x8 af[4], bfr[4];
#pragma unroll
        for (int i = 0; i < 4; i++) af[i]  = *(const bf16x8*)(&As[wm + i * 16 + mr][qk]);
#pragma unroll
        for (int j = 0; j < 4; j++) bfr[j] = *(const bf16x8*)(&Bs[wn + j * 16 + mr][qk]);
#pragma unroll
        for (int i = 0; i < 4; i++)
#pragma unroll
            for (int j = 0; j < 4; j++)
                acc[i][j] = __builtin_amdgcn_mfma_f32_16x16x32_bf16(af[i], bfr[j], acc[i][j], 0, 0, 0);
        __syncthreads();
    }

    const int cr = (lane >> 4) * 4;
    const int cc = lane & 15;
#pragma unroll
    for (int i = 0; i < 4; i++) {
#pragma unroll
        for (int j = 0; j < 4; j++) {
            const long m = m0 + wm + i * 16 + cr;
            const long n = n0 + wn + j * 16 + cc;
            if (F32OUT) {
                float* C = (float*)Cv;
#pragma unroll
                for (int r = 0; r < 4; r++) C[(m + r) * ldc + n] = acc[i][j][r];
            } else {
                u16* C = (u16*)Cv;
#pragma unroll
                for (int r = 0; r < 4; r++) C[(m + r) * ldc + n] = f2bf_h(acc[i][j][r]);
            }
        }
    }
}

// ---------------------------------------------------------------------------
// GEMM with fp32 A (converted to bf16 at staging via v_cvt; padded LDS) and
// bf16 BT staged via global_load_lds. Used only for the gate GEMM (N=1024).
// ---------------------------------------------------------------------------
#define LDA 40

__global__ __launch_bounds__(256) void gemm_a32_kernel(const float* __restrict__ A,
                                                       const u16* __restrict__ BT,
                                                       u16* __restrict__ C,
                                                       int M, int N, int K, int ldc) {
    __shared__ __attribute__((aligned(16))) u16 As[128][LDA];
    __shared__ __attribute__((aligned(16))) u16 Bs[128][32];
    const int tid  = threadIdx.x;
    const int lane = tid & 63;
    const int wave = tid >> 6;
    const int wm   = (wave >> 1) * 64;
    const int wn   = (wave & 1) * 64;
    const long m0  = (long)blockIdx.y * 128;
    const long n0  = (long)blockIdx.x * 128;

    const f32x4 zero = {0.f, 0.f, 0.f, 0.f};
    f32x4 acc[4][4];
#pragma unroll
    for (int i = 0; i < 4; i++)
#pragma unroll
        for (int j = 0; j < 4; j++) acc[i][j] = zero;

    const int r0 = tid >> 2;
    const int c0 = (tid & 3) * 8;
    const float* Ag = A + (m0 + r0) * K + c0;
    const u16* Bg = BT + (n0 + r0) * K + c0;
    u16* BsW  = &Bs[wave * 16][0];
    u16* BsW2 = &Bs[wave * 16 + 64][0];

    for (int k0 = 0; k0 < K; k0 += 32) {
        gl2lds16(Bg + k0, BsW);
        gl2lds16(Bg + (long)64 * K + k0, BsW2);
        f32x4 af0 = *(const f32x4*)(Ag + k0);
        f32x4 af1 = *(const f32x4*)(Ag + k0 + 4);
        f32x4 ag0 = *(const f32x4*)(Ag + (long)64 * K + k0);
        f32x4 ag1 = *(const f32x4*)(Ag + (long)64 * K + k0 + 4);
        u16x8 a0, a1;
#pragma unroll
        for (int r = 0; r < 4; r++) {
            a0[r] = f2bf_h(af0[r]); a0[r + 4] = f2bf_h(af1[r]);
            a1[r] = f2bf_h(ag0[r]); a1[r + 4] = f2bf_h(ag1[r]);
        }
        *(u16x8*)(&As[r0][c0])      = a0;
        *(u16x8*)(&As[r0 + 64][c0]) = a1;
        __syncthreads();
        const int qk = (lane >> 4) * 8;
        const int mr = lane & 15;
        bf16x8 af[4], bfr[4];
#pragma unroll
        for (int i = 0; i < 4; i++) af[i]  = *(const bf16x8*)(&As[wm + i * 16 + mr][qk]);
#pragma unroll
        for (int j = 0; j < 4; j++) bfr[j] = *(const bf16x8*)(&Bs[wn + j * 16 + mr][qk]);
#pragma unroll
        for (int i = 0; i < 4; i++)
#pragma unroll
            for (int j = 0; j < 4; j++)
                acc[i][j] = __builtin_amdgcn_mfma_f32_16x16x32_bf16(af[i], bfr[j], acc[i][j], 0, 0, 0);
        __syncthreads();
    }

    const int cr = (lane >> 4) * 4;
    const int cc = lane & 15;
#pragma unroll
    for (int i = 0; i < 4; i++) {
#pragma unroll
        for (int j = 0; j < 4; j++) {
            const long m = m0 + wm + i * 16 + cr;
            const long n = n0 + wn + j * 16 + cc;
#pragma unroll
            for (int r = 0; r < 4; r++) C[(m + r) * ldc + n] = f2bf_h(acc[i][j][r]);
        }
    }
}

// ---------------------------------------------------------------------------
// Fused: in-place L2-normalize q (x 1/16) and k per head; beta & dec per head.
// Reads bf16 xb (cvt output) -- R4 configuration.
// ---------------------------------------------------------------------------
__global__ __launch_bounds__(1024) void norm_beta_kernel(
    const u16* __restrict__ xb, u16* __restrict__ Y,
    const float* __restrict__ Wb, const float* __restrict__ Wa,
    const float* __restrict__ A_log, const float* __restrict__ dt_bias,
    float* __restrict__ beta, float* __restrict__ dec) {
    const long row = blockIdx.x;
    const int c = threadIdx.x;
    const int h = c >> 8;
    float qv = bf2f(Y[row * 3072 + c]);
    float kv = bf2f(Y[row * 3072 + 1024 + c]);
    float xv = bf2f(xb[row * 1024 + c]);
    float vals[10];
    vals[0] = qv * qv;
    vals[1] = kv * kv;
#pragma unroll
    for (int hh = 0; hh < 4; hh++) vals[2 + hh] = xv * Wb[c * 4 + hh];
#pragma unroll
    for (int hh = 0; hh < 4; hh++) vals[6 + hh] = xv * Wa[c * 4 + hh];
#pragma unroll
    for (int i = 0; i < 10; i++)
        for (int off = 32; off; off >>= 1) vals[i] += __shfl_xor(vals[i], off, 64);

    __shared__ float wred[16][10];
    __shared__ float sQ[4], sK[4];
    const int w = c >> 6;
    if ((c & 63) == 0) {
#pragma unroll
        for (int i = 0; i < 10; i++) wred[w][i] = vals[i];
    }
    __syncthreads();
    if (c < 4) {
        float s = wred[c * 4 + 0][0] + wred[c * 4 + 1][0] + wred[c * 4 + 2][0] + wred[c * 4 + 3][0];
        sQ[c] = rsqrtf(s + 1e-6f) * 0.0625f;
    } else if (c < 8) {
        int hh = c - 4;
        float s = wred[hh * 4 + 0][1] + wred[hh * 4 + 1][1] + wred[hh * 4 + 2][1] + wred[hh * 4 + 3][1];
        sK[hh] = rsqrtf(s + 1e-6f);
    } else if (c < 12) {
        int hh = c - 8;
        float s = 0.f;
        for (int ww = 0; ww < 16; ww++) s += wred[ww][2 + hh];
        beta[row * 4 + hh] = 1.f / (1.f + expf(-s));
    } else if (c < 16) {
        int hh = c - 12;
        float s = 0.f;
        for (int ww = 0; ww < 16; ww++) s += wred[ww][6 + hh];
        float z = s + dt_bias[hh];
        float sp = (z > 0.f) ? (z + log1pf(expf(-z))) : log1pf(expf(z));
        dec[row * 4 + hh] = expf(-expf(A_log[hh]) * sp);
    }
    __syncthreads();
    Y[row * 3072 + c]        = f2bf_h(qv * sQ[h]);
    Y[row * 3072 + 1024 + c] = f2bf_h(kv * sK[h]);
}

// ---------------------------------------------------------------------------
// PASS A (chunk-parallel prep): per (bh, chunk) compute A matrix, T=(I+A)^-1
// via nilpotent doubling, and M matrix. Writes T, M (bf16 [64][64]) to global.
// Also writes the per-chunk scalar tables sfg[bh*64+c][256]:
//   [0:64)=gam  [64:128)=beta*gam  [128:192)=beta  [192:256)=ksc (gamL/gam)
// ---------------------------------------------------------------------------
__global__ __launch_bounds__(256) void prep_kernel(const u16* __restrict__ Y,
                                                   const float* __restrict__ beta,
                                                   const float* __restrict__ dec,
                                                   u16* __restrict__ Tg,
                                                   u16* __restrict__ Mg,
                                                   float* __restrict__ sfg) {
    __shared__ __attribute__((aligned(16))) u16 lds[38400];
    __shared__ float sf[320];
    u16* KS  = lds;            // 64 x 264
    u16* QS  = lds + 16896;    // 64 x 264
    u16* AM  = lds + 33792;    // 64 x 72
    // overlays (valid after G phase; KS/QS dead):
    u16* Tm  = lds;            // 64 x 72
    u16* AMT = lds + 4608;
    u16* MP  = lds + 9216;
    u16* MPT = lds + 13824;

    const int bx = blockIdx.x;
    const int bh = bx >> 6, c = bx & 63;
    const int b = bh >> 2, h = bh & 3;
    const int tid = threadIdx.x, lane = tid & 63, wv = tid >> 6;
    const int quad = lane >> 4, l15 = lane & 15;
    const int tld = tid >> 2, seg = tid & 3;
    const long bt0 = (long)b * 4096 + c * 64;
    u16* Tc = Tg + (size_t)(bh * 64 + c) * 4096;
    u16* Mc = Mg + (size_t)(bh * 64 + c) * 4096;
    const f32x4 z4 = {0.f, 0.f, 0.f, 0.f};

    // ---- stage K,Q; gamma prefix ----
    {
        const long rb = (bt0 + tld) * 3072 + h * 256 + seg * 64;
#pragma unroll
        for (int i = 0; i < 8; i++) {
            *(u16x8*)&KS[tld * 264 + seg * 64 + i * 8] = *(const u16x8*)&Y[rb + 1024 + i * 8];
            *(u16x8*)&QS[tld * 264 + seg * 64 + i * 8] = *(const u16x8*)&Y[rb + i * 8];
        }
    }
    if (wv == 0) {
        float d   = dec [(bt0 + lane) * 4 + h];
        float bt_ = beta[(bt0 + lane) * 4 + h];
        float lg = log2f(fmaxf(d, 1e-30f));
#pragma unroll
        for (int off = 1; off < 64; off <<= 1) {
            float o = __shfl_up(lg, off, 64);
            if (lane >= off) lg += o;
        }
        sf[lane] = lg; sf[192 + lane] = bt_;
        float lgL = __shfl(lg, 63, 64);
        float g = exp2f(lg);
        float* sfc = sfg + (size_t)(bh * 64 + c) * 256;
        sfc[lane]       = g;
        sfc[64 + lane]  = bt_ * g;
        sfc[128 + lane] = bt_;
        sfc[192 + lane] = exp2f(lgL - lg);
    }
    __syncthreads();   // B1

    // ---- G phase: waves 0-1 -> A matrix (LDS); waves 2-3 -> M (global) ----
    {
        const u16* Ab = (wv < 2) ? KS : QS;
        const int mb = (wv & 1) * 32;
        f32x4 g[2][4];
#pragma unroll
        for (int mi = 0; mi < 2; mi++)
#pragma unroll
            for (int sj = 0; sj < 4; sj++) g[mi][sj] = z4;
#pragma unroll 2
        for (int k0 = 0; k0 < 256; k0 += 32) {
            bf16x8 bfr[4];
#pragma unroll
            for (int sj = 0; sj < 4; sj++) bfr[sj] = ldfrag(KS, 264, sj * 16, k0, lane);
#pragma unroll
            for (int mi = 0; mi < 2; mi++) {
                bf16x8 af = ldfrag(Ab, 264, mb + mi * 16, k0, lane);
#pragma unroll
                for (int sj = 0; sj < 4; sj++)
                    g[mi][sj] = __builtin_amdgcn_mfma_f32_16x16x32_bf16(af, bfr[sj], g[mi][sj], 0, 0, 0);
            }
        }
#pragma unroll
        for (int mi = 0; mi < 2; mi++)
#pragma unroll
            for (int sj = 0; sj < 4; sj++)
#pragma unroll
                for (int r = 0; r < 4; r++) {
                    const int t_ = mb + mi * 16 + quad * 4 + r, s_ = sj * 16 + l15;
                    if (wv < 2)
                        AM[t_ * 72 + s_] = (s_ < t_) ? f2bf_h(sf[192 + t_] * exp2f(sf[t_] - sf[s_]) * g[mi][sj][r]) : (u16)0;
                    else
                        Mc[t_ * 64 + s_] = (s_ <= t_) ? f2bf_h(exp2f(sf[t_] - sf[s_]) * g[mi][sj][r]) : (u16)0;
                }
    }
    __syncthreads();   // B2 (KS/QS dead)

    // ---- solve init: T = I - A, A^T ----
    {
        const int t_ = tid >> 2;
#pragma unroll
        for (int i = 0; i < 16; i++) {
            const int s_ = (tid & 3) * 16 + i;
            const u16 a = AM[t_ * 72 + s_];
            Tm[t_ * 72 + s_] = (t_ == s_) ? (u16)0x3F80 : (u16)(a ^ 0x8000);
            AMT[s_ * 72 + t_] = a;
        }
    }
    __syncthreads();   // B3

    // ---- r1: Mp = N*N ----
    {
        f32x4 sq[4];
#pragma unroll
        for (int sj = 0; sj < 4; sj++) sq[sj] = z4;
#pragma unroll
        for (int k0 = 0; k0 < 64; k0 += 32) {
            bf16x8 a = ldfrag(AM, 72, 16 * wv, k0, lane);
#pragma unroll
            for (int sj = 0; sj < 4; sj++) {
                bf16x8 bb = ldfrag(AMT, 72, sj * 16, k0, lane);
                sq[sj] = __builtin_amdgcn_mfma_f32_16x16x32_bf16(a, bb, sq[sj], 0, 0, 0);
            }
        }
#pragma unroll
        for (int sj = 0; sj < 4; sj++)
#pragma unroll
            for (int r = 0; r < 4; r++) {
                const int t_ = 16 * wv + quad * 4 + r, s_ = sj * 16 + l15;
                const u16 vbf = f2bf_h(sq[sj][r]);
                MP[t_ * 72 + s_] = vbf;
                MPT[s_ * 72 + t_] = vbf;
            }
        __syncthreads();   // B4
    }

    // ---- fused rounds: T += T*Mp ; Mp <- Mp*Mp (skip on last) ----
#pragma unroll 1
    for (int jj = 0; jj < 5; jj++) {
        const bool last = (jj == 4);
        f32x4 pp[4], sq[4];
#pragma unroll
        for (int sj = 0; sj < 4; sj++) {
            sq[sj] = z4;
#pragma unroll
            for (int r = 0; r < 4; r++)
                pp[sj][r] = bf2f(Tm[(16 * wv + quad * 4 + r) * 72 + sj * 16 + l15]);
        }
#pragma unroll
        for (int k0 = 0; k0 < 64; k0 += 32) {
            bf16x8 at = ldfrag(Tm, 72, 16 * wv, k0, lane);
            bf16x8 am = ldfrag(MP, 72, 16 * wv, k0, lane);
#pragma unroll
            for (int sj = 0; sj < 4; sj++) {
                bf16x8 bb = ldfrag(MPT, 72, sj * 16, k0, lane);
                pp[sj] = __builtin_amdgcn_mfma_f32_16x16x32_bf16(at, bb, pp[sj], 0, 0, 0);
                if (!last) sq[sj] = __builtin_amdgcn_mfma_f32_16x16x32_bf16(am, bb, sq[sj], 0, 0, 0);
            }
        }
        __syncthreads();
#pragma unroll
        for (int sj = 0; sj < 4; sj++)
#pragma unroll
            for (int r = 0; r < 4; r++) {
                const int t_ = 16 * wv + quad * 4 + r, s_ = sj * 16 + l15;
                Tm[t_ * 72 + s_] = f2bf_h(pp[sj][r]);
                if (!last) {
                    const u16 vbf = f2bf_h(sq[sj][r]);
                    MP[t_ * 72 + s_] = vbf;
                    MPT[s_ * 72 + t_] = vbf;
                }
            }
        __syncthreads();
    }

    // ---- write T to global ----
    {
        const int t_ = tid >> 2;
#pragma unroll
        for (int i = 0; i < 16; i++) {
            const int s_ = (tid & 3) * 16 + i;
            Tc[t_ * 64 + s_] = Tm[t_ * 72 + s_];
        }
    }
}

// ---------------------------------------------------------------------------
// PASS B (sequential scan): grid 64 = bh(16) x dvs(4), 512 threads / 8 waves,
// ROLE-SPLIT: waves 0-3 = K-role (wq = wv&3), waves 4-7 = Q-role.
// R6: XCD-sibling swizzle -- the 4 dvs blocks sharing one bh's K/Q are mapped
// to blockIdx values == (bh&7) mod 8, so they land on the SAME XCD L2 and K/Q
// is fetched from HBM once instead of 4x. Pure relabeling (correctness-safe).
// ---------------------------------------------------------------------------
struct Frag { bf16x8 f[8]; };

__global__ __launch_bounds__(512, 2) void scan_kernel(const u16* __restrict__ Y,
                                                      const float* __restrict__ sfg,
                                                      const u16* __restrict__ Tg,
                                                      const u16* __restrict__ Mg,
                                                      u16* __restrict__ Ob) {
    __shared__ __attribute__((aligned(16))) u16 KT[4 * 4616];   // [dk-panel][dk6*72 + t_rot]
    __shared__ __attribute__((aligned(16))) u16 ST[64 * 264];   // [dv][dk]
    __shared__ __attribute__((aligned(16))) u16 RHST[64 * 72];  // [dv][t]
    __shared__ __attribute__((aligned(16))) u16 UTp[64 * 72];   // [dv][t] plain
    __shared__ __attribute__((aligned(16))) u16 UTk[64 * 72];   // [dv][t] ksc-folded

    const int px = blockIdx.x;
    // siblings {g, g+8, g+16, g+24} (same bh) are == same value mod 8 -> same XCD
    const int bh = (px & 7) | ((px >> 5) << 3);
    const int dvs = (px >> 3) & 3;
    const int b = bh >> 2, h = bh & 3;
    const int tid = threadIdx.x, lane = tid & 63, wv = tid >> 6;
    const int wq = wv & 3;           // t-group (16 t rows)
    const int isQ = wv >> 2;         // role: 0 = K-side, 1 = Q-side
    const int quad = lane >> 4, l15 = lane & 15;
    const int tW = 16 * wq + l15;                     // lane's t (output col)
    const int tph = 16 * ((wq + quad) & 3) + l15;     // rotated t for KT writes
    int toff[4];                                      // KT read t-rotation per dk-tile
#pragma unroll
    for (int j = 0; j < 4; j++) toff[j] = ((((j << 1) + (l15 >> 3)) & 3) << 4);
    const f32x4 z4 = {0.f, 0.f, 0.f, 0.f};

    f32x4 Sacc[2][4];   // [dv-tile within role half][dk-tile within wq slice]
#pragma unroll
    for (int i = 0; i < 2; i++)
#pragma unroll
        for (int j = 0; j < 4; j++) Sacc[i][j] = z4;
    for (int i = tid; i < 64 * 264; i += 512) ST[i] = 0;
    __syncthreads();

    const long roleOff = isQ ? 0 : 1024;   // q at +0, k at +1024 in Y rows
    Frag F0, F1;
    {
        const u16* Pg = Y + ((long)b * 4096) * 3072 + roleOff + h * 256;
#pragma unroll
        for (int i = 0; i < 8; i++) F0.f[i] = ldfrag(Pg, 3072, 16 * wq, i * 32, lane);
    }

    // deferred-O carry state (Q-role only)
    f32x4 oaccP[4];
#pragma unroll
    for (int j = 0; j < 4; j++) oaccP[j] = z4;
    bf16x8 amP0 = {}, amP1 = {};
    long obP = 0;
    int havePrev = 0;

    auto body = [&](Frag& cur, Frag& nxt, int c) {
        const long bt0 = (long)b * 4096 + (long)c * 64;
        const int cn = (c < 63) ? c + 1 : 63;

        // ---- issue NEXT-chunk fragment prefetch (role's operand only) ----
        {
            const u16* Pg = Y + ((long)b * 4096 + (long)cn * 64) * 3072 + roleOff + h * 256;
#pragma unroll
            for (int i = 0; i < 8; i++) nxt.f[i] = ldfrag(Pg, 3072, 16 * wq, i * 32, lane);
        }

        // ---- current-chunk T + scalars (both roles) ----
        const u16* Tc = Tg + (size_t)(bh * 64 + c) * 4096;
        bf16x8 at0 = ldfrag(Tc, 64, 16 * wq, 0, lane);
        bf16x8 at1 = ldfrag(Tc, 64, 16 * wq, 32, lane);
        const float* sfc = sfg + (size_t)(bh * 64 + c) * 256;
        const float gam_l = sfc[tW];
        const float bg_l  = sfc[64 + tW];
        const float bet_l = sfc[128 + tW];
        const float ksc_l = sfc[192 + tW];
        const float gL    = sfc[63];

        u16x4 v4[4];
        if (!isQ) {
            // K-role: V loads (for RHS)
            const u16* Vr = Y + (bt0 + tW) * 3072 + 2048 + h * 256 + dvs * 64;
#pragma unroll
            for (int j = 0; j < 4; j++) v4[j] = *(const u16x4*)(Vr + j * 16 + quad * 4);
        } else {
            // Q-role: M loads + deferred O of previous chunk
            const u16* Mc = Mg + (size_t)(bh * 64 + c) * 4096;
            bf16x8 amN0 = ldfrag(Mc, 64, 16 * wq, 0, lane);
            bf16x8 amN1 = ldfrag(Mc, 64, 16 * wq, 32, lane);
            if (havePrev) {
#pragma unroll
                for (int sj = 0; sj < 4; sj++) {
                    bf16x8 ua0 = ldfrag(UTp, 72, sj * 16, 0, lane);
                    oaccP[sj] = __builtin_amdgcn_mfma_f32_16x16x32_bf16(ua0, amP0, oaccP[sj], 0, 0, 0);
                    bf16x8 ua1 = ldfrag(UTp, 72, sj * 16, 32, lane);
                    oaccP[sj] = __builtin_amdgcn_mfma_f32_16x16x32_bf16(ua1, amP1, oaccP[sj], 0, 0, 0);
                }
#pragma unroll
                for (int sj = 0; sj < 4; sj++) {
                    u16x4 o4;
#pragma unroll
                    for (int r = 0; r < 4; r++) o4[r] = f2bf_h(oaccP[sj][r]);
                    *(u16x4*)(Ob + obP + sj * 16 + quad * 4) = o4;
                }
            }
            amP0 = amN0; amP1 = amN1;
        }

        // ---- P phase: p = ST @ role-frag, C[dv-tile][t=wq group] ----
        f32x4 p[4];
#pragma unroll
        for (int j = 0; j < 4; j++) p[j] = z4;
#pragma unroll
        for (int i = 0; i < 8; i++) {
            bf16x8 sfr[4];
#pragma unroll
            for (int j = 0; j < 4; j++) sfr[j] = ldfrag(ST, 264, j * 16, i * 32, lane);
#pragma unroll
            for (int j = 0; j < 4; j++)
                p[j] = __builtin_amdgcn_mfma_f32_16x16x32_bf16(sfr[j], cur.f[i], p[j], 0, 0, 0);
        }

        if (!isQ) {
            // ---- KT build from cur (K frags): raw bits, rotated t ----
#pragma unroll
            for (int i = 0; i < 8; i++) {
                const u16* src = (const u16*)&cur.f[i];
                u16* dst = KT + (i >> 1) * 4616 + ((i & 1) * 32 + quad * 8) * 72 + tph;
#pragma unroll
                for (int jj = 0; jj < 8; jj++) dst[jj * 72] = src[jj];
            }
            // ---- RHS = beta*V - beta*gam*pk ----
#pragma unroll
            for (int j = 0; j < 4; j++)
#pragma unroll
                for (int r = 0; r < 4; r++) {
                    const int row = j * 16 + quad * 4 + r;
                    RHST[row * 72 + tW] = f2bf_h(bet_l * bf2f(v4[j][r]) - bg_l * p[j][r]);
                }
        } else {
            // ---- oacc = gam*pq (becomes next chunk's deferred-O base) ----
#pragma unroll
            for (int j = 0; j < 4; j++)
#pragma unroll
                for (int r = 0; r < 4; r++) oaccP[j][r] = gam_l * p[j][r];
            obP = (bt0 + tW) * 1024 + h * 256 + (long)dvs * 64;
            havePrev = 1;
        }
        block_barrier();   // B2 (RHST + KT visible)

        // ---- U phase: role K does dv tiles 0-1, role Q does 2-3 ----
        {
#pragma unroll
            for (int s2 = 0; s2 < 2; s2++) {
                const int sj = isQ * 2 + s2;
                f32x4 uu = z4;
                bf16x8 ra0 = ldfrag(RHST, 72, sj * 16, 0, lane);
                uu = __builtin_amdgcn_mfma_f32_16x16x32_bf16(ra0, at0, uu, 0, 0, 0);
                bf16x8 ra1 = ldfrag(RHST, 72, sj * 16, 32, lane);
                uu = __builtin_amdgcn_mfma_f32_16x16x32_bf16(ra1, at1, uu, 0, 0, 0);
#pragma unroll
                for (int r = 0; r < 4; r++) {
                    const int row = sj * 16 + quad * 4 + r;
                    UTp[row * 72 + tW] = f2bf_h(uu[r]);
                    UTk[row * 72 + tW] = f2bf_h(ksc_l * uu[r]);
                }
            }
        }
        block_barrier();   // B3 (UTp/UTk visible)

        // ---- S update: dv-half = role, dk slice = wq ----
        {
#pragma unroll
            for (int i = 0; i < 2; i++)
#pragma unroll
                for (int j = 0; j < 4; j++) Sacc[i][j] *= gL;
            const u16* KTp = KT + wq * 4616;
#pragma unroll
            for (int k0 = 0; k0 < 64; k0 += 32) {
                bf16x8 au[2], bk[4];
#pragma unroll
                for (int i = 0; i < 2; i++) au[i] = ldfrag(UTk, 72, isQ * 32 + i * 16, k0, lane);
#pragma unroll
                for (int j = 0; j < 4; j++)
                    bk[j] = *(const bf16x8*)(KTp + (size_t)(j * 16 + l15) * 72 +
                                             ((k0 + quad * 8 + toff[j]) & 63));
#pragma unroll
                for (int i = 0; i < 2; i++)
#pragma unroll
                    for (int j = 0; j < 4; j++)
                        Sacc[i][j] = __builtin_amdgcn_mfma_f32_16x16x32_bf16(au[i], bk[j], Sacc[i][j], 0, 0, 0);
            }
#pragma unroll
            for (int i = 0; i < 2; i++)
#pragma unroll
                for (int j = 0; j < 4; j++)
#pragma unroll
                    for (int r = 0; r < 4; r++)
                        ST[(isQ * 32 + i * 16 + quad * 4 + r) * 264 + wq * 64 + j * 16 + l15] = f2bf_h(Sacc[i][j][r]);
        }
        block_barrier();   // B4 (ST visible for next chunk)
    };

#pragma unroll 1
    for (int c = 0; c < 64; c += 2) {
        body(F0, F1, c);
        body(F1, F0, c + 1);
    }

    // ---- final deferred O (chunk 63, Q-role) ----
    if (isQ) {
#pragma unroll
        for (int sj = 0; sj < 4; sj++) {
            bf16x8 ua0 = ldfrag(UTp, 72, sj * 16, 0, lane);
            oaccP[sj] = __builtin_amdgcn_mfma_f32_16x16x32_bf16(ua0, amP0, oaccP[sj], 0, 0, 0);
            bf16x8 ua1 = ldfrag(UTp, 72, sj * 16, 32, lane);
            oaccP[sj] = __builtin_amdgcn_mfma_f32_16x16x32_bf16(ua1, amP1, oaccP[sj], 0, 0, 0);
        }
#pragma unroll
        for (int sj = 0; sj < 4; sj++) {
            u16x4 o4;
#pragma unroll
            for (int r = 0; r < 4; r++) o4[r] = f2bf_h(oaccP[sj][r]);
            *(u16x4*)(Ob + obP + sj * 16 + quad * 4) = o4;
        }
    }
}

// ---------------------------------------------------------------------------
// Gated RMSNorm + SiLU; writes og IN PLACE into G.
// ---------------------------------------------------------------------------
__global__ __launch_bounds__(256) void gate_norm_kernel(const u16* __restrict__ O,
                                                        u16* __restrict__ G,
                                                        const float* __restrict__ norm_w) {
    const long row = blockIdx.x >> 2;
    const int h = blockIdx.x & 3;
    const int dv = threadIdx.x;
    const long idx = row * 1024 + h * 256 + dv;
    float o = bf2f(O[idx]);
    float s = o * o;
#pragma unroll
    for (int off = 32; off; off >>= 1) s += __shfl_xor(s, off, 64);
    __shared__ float wsum[4];
    if ((dv & 63) == 0) wsum[dv >> 6] = s;
    __syncthreads();
    const float tot = wsum[0] + wsum[1] + wsum[2] + wsum[3];
    const float r = rsqrtf(tot * (1.f / 256.f) + 1e-5f);
    const float g = bf2f(G[idx]);
    const float val = o * r * norm_w[dv] * (g / (1.f + expf(-g)));
    G[idx] = f2bf_h(val);
}

// ---------------------------------------------------------------------------
extern "C" void kernel_launch(void* const* d_in, const int* in_sizes, int n_in,
                              void* d_out, int out_size, void* d_ws, size_t ws_size,
                              hipStream_t stream) {
    const float* x       = (const float*)d_in[0];
    const float* Wq      = (const float*)d_in[1];
    const float* Wk      = (const float*)d_in[2];
    const float* Wv      = (const float*)d_in[3];
    const float* Wb      = (const float*)d_in[4];
    const float* Wa      = (const float*)d_in[5];
    const float* A_log   = (const float*)d_in[6];
    const float* dt_bias = (const float*)d_in[7];
    const float* Wg      = (const float*)d_in[8];
    const float* norm_w  = (const float*)d_in[9];
    const float* Wo      = (const float*)d_in[10];

    // workspace: identical 171 MB footprint as previous rounds (proven to fit).
    char* p = (char*)d_ws;
    u16*   WT   = (u16*)p;   p += (size_t)5120 * 1024 * 2;   // WqT|WkT|WvT|WgT|WoT bf16
    u16*   Y    = (u16*)p;   p += (size_t)16384 * 3072 * 2;  // q|k|v bf16
    u16*   G    = (u16*)p;   p += (size_t)16384 * 1024 * 2;  // T|M (prep+scan), then gate/og
    u16*   XO   = (u16*)p;   p += (size_t)16384 * 1024 * 2;  // xb (early), O (scan output)
    float* beta = (float*)p; p += (size_t)16384 * 4 * 4;
    float* dec  = (float*)p; p += (size_t)16384 * 4 * 4;

    u16* Tg = G;                                  // [16*64][64*64] bf16, 8.4 MB
    u16* Mg = G + (size_t)1024 * 4096;            // same, next 8.4 MB
    // sfg (1 MB) overlays WqT, which is dead after the big QKV GEMM.
    float* sfg = (float*)WT;                      // [16*64][256] f32

    cvt_kernel<<<16384, 256, 0, stream>>>(x, XO);

    dim3 tb(32, 8), tg(32, 32);
    transpose_kernel<<<tg, tb, 0, stream>>>(Wq, WT + (size_t)0 * 1024 * 1024);
    transpose_kernel<<<tg, tb, 0, stream>>>(Wk, WT + (size_t)1 * 1024 * 1024);
    transpose_kernel<<<tg, tb, 0, stream>>>(Wv, WT + (size_t)2 * 1024 * 1024);
    transpose_kernel<<<tg, tb, 0, stream>>>(Wg, WT + (size_t)3 * 1024 * 1024);
    transpose_kernel<<<tg, tb, 0, stream>>>(Wo, WT + (size_t)4 * 1024 * 1024);

    // Y = xb @ [Wq|Wk|Wv]   (M=16384, N=3072, K=1024; bf16 A, gll staging)
    gemm_kernel<0><<<dim3(3072 / 128, 16384 / 128), 256, 0, stream>>>(
        XO, WT, (void*)Y, 16384, 3072, 1024, 3072);

    norm_beta_kernel<<<16384, 1024, 0, stream>>>(XO, Y, Wb, Wa, A_log, dt_bias, beta, dec);

    // prep also writes sfg into the dead WqT region
    prep_kernel<<<1024, 256, 0, stream>>>(Y, beta, dec, Tg, Mg, sfg);

    // xb dead; scan writes O into XO
    scan_kernel<<<64, 512, 0, stream>>>(Y, sfg, Tg, Mg, XO);

    // gate = x @ Wg (fp32 A; overwrites T/M region -> after scan)
    gemm_a32_kernel<<<dim3(1024 / 128, 16384 / 128), 256, 0, stream>>>(
        x, WT + (size_t)3072 * 1024, G, 16384, 1024, 1024, 1024);

    gate_norm_kernel<<<16384 * 4, 256, 0, stream>>>(XO, G, norm_w);

    // out = og @ Wo   (fp32 out)
    gemm_kernel<1><<<dim3(1024 / 128, 16384 / 128), 256, 0, stream>>>(
        G, WT + (size_t)4096 * 1024, d_out, 16384, 1024, 1024, 1024);
}

// Round 7
// 898.817 us; speedup vs baseline: 1.1678x; 1.1087x over previous
//
#include <hip/hip_runtime.h>

typedef unsigned short u16;
typedef __bf16 bf16x8 __attribute__((ext_vector_type(8)));
typedef u16 u16x8 __attribute__((ext_vector_type(8)));
typedef u16 u16x4 __attribute__((ext_vector_type(4)));
typedef float f32x4 __attribute__((ext_vector_type(4)));

__device__ __forceinline__ float bf2f(u16 v) {
    union { unsigned u; float f; } c; c.u = ((unsigned)v) << 16; return c.f;
}
// HW RNE f32->bf16 (single v_cvt)
__device__ __forceinline__ u16 f2bf_h(float f) {
    __bf16 h = (__bf16)f;
    union { __bf16 h; u16 u; } c; c.h = h; return c.u;
}

// MFMA fragment load (works for LDS or global pointers): LEFT operand from
// [m][k] row-major, or RIGHT operand from [n][k] row-major.
__device__ __forceinline__ bf16x8 ldfrag(const u16* base, int stride, int row0, int k0, int lane) {
    return *(const bf16x8*)(base + (size_t)(row0 + (lane & 15)) * stride + k0 + (lane >> 4) * 8);
}

// Raw workgroup barrier: commits LDS (lgkmcnt only) but does NOT drain vmcnt.
__device__ __forceinline__ void block_barrier() {
    __builtin_amdgcn_sched_barrier(0);
    asm volatile("s_waitcnt lgkmcnt(0)");
    __builtin_amdgcn_s_barrier();
    __builtin_amdgcn_sched_barrier(0);
}

// async global->LDS, 16 B per lane. LDS dest must be wave-uniform base.
__device__ __forceinline__ void gl2lds16(const void* g, void* l) {
    __builtin_amdgcn_global_load_lds(
        (const __attribute__((address_space(1))) unsigned int*)g,
        (__attribute__((address_space(3))) unsigned int*)l, 16, 0, 0);
}

// ---------------------------------------------------------------------------
// fp32 -> bf16 elementwise convert
// ---------------------------------------------------------------------------
__global__ __launch_bounds__(256) void cvt_kernel(const float* __restrict__ src,
                                                  u16* __restrict__ dst) {
    const long i = ((long)blockIdx.x * 256 + threadIdx.x) * 4;
    f32x4 v = *(const f32x4*)(src + i);
    u16x4 o;
#pragma unroll
    for (int r = 0; r < 4; r++) o[r] = f2bf_h(v[r]);
    *(u16x4*)(dst + i) = o;
}

// ---------------------------------------------------------------------------
// 5 weight transposes in ONE launch: z selects the weight.
// src fp32 [1024,1024] (k,n) -> dst bf16 (n,k) at WT + z*1M
// ---------------------------------------------------------------------------
__global__ __launch_bounds__(256) void transpose5_kernel(const float* __restrict__ s0,
                                                         const float* __restrict__ s1,
                                                         const float* __restrict__ s2,
                                                         const float* __restrict__ s3,
                                                         const float* __restrict__ s4,
                                                         u16* __restrict__ dstBase) {
    __shared__ float tile[32][33];
    const int z = blockIdx.z;
    const float* src = (z == 0) ? s0 : (z == 1) ? s1 : (z == 2) ? s2 : (z == 3) ? s3 : s4;
    u16* dst = dstBase + (size_t)z * 1024 * 1024;
    const int n0 = blockIdx.x * 32, k0 = blockIdx.y * 32;
    const int tx = threadIdx.x, ty = threadIdx.y;   // 32 x 8
#pragma unroll
    for (int i = 0; i < 32; i += 8)
        tile[ty + i][tx] = src[(long)(k0 + ty + i) * 1024 + n0 + tx];
    __syncthreads();
#pragma unroll
    for (int i = 0; i < 32; i += 8)
        dst[(long)(n0 + ty + i) * 1024 + k0 + tx] = f2bf_h(tile[tx][ty + i]);
}

// ---------------------------------------------------------------------------
// MFMA GEMM: C[M,N] = A[M,K](bf16) * BT[N,K](bf16)^T, fp32 accum.
// A and B staged via global_load_lds (linear [128][32] LDS).
// ---------------------------------------------------------------------------
template <int F32OUT>
__global__ __launch_bounds__(256) void gemm_kernel(const u16* __restrict__ A,
                                                   const u16* __restrict__ BT,
                                                   void* __restrict__ Cv,
                                                   int M, int N, int K, int ldc) {
    __shared__ __attribute__((aligned(16))) u16 As[128][32];
    __shared__ __attribute__((aligned(16))) u16 Bs[128][32];
    const int tid  = threadIdx.x;
    const int lane = tid & 63;
    const int wave = tid >> 6;
    const int wm   = (wave >> 1) * 64;
    const int wn   = (wave & 1) * 64;
    const long m0  = (long)blockIdx.y * 128;
    const long n0  = (long)blockIdx.x * 128;

    const f32x4 zero = {0.f, 0.f, 0.f, 0.f};
    f32x4 acc[4][4];
#pragma unroll
    for (int i = 0; i < 4; i++)
#pragma unroll
        for (int j = 0; j < 4; j++) acc[i][j] = zero;

    const int r0 = tid >> 2;
    const int c0 = (tid & 3) * 8;
    const u16* Ag = A + (m0 + r0) * K + c0;
    const u16* Bg = BT + (n0 + r0) * K + c0;
    u16* AsW  = &As[wave * 16][0];
    u16* AsW2 = &As[wave * 16 + 64][0];
    u16* BsW  = &Bs[wave * 16][0];
    u16* BsW2 = &Bs[wave * 16 + 64][0];

    for (int k0 = 0; k0 < K; k0 += 32) {
        gl2lds16(Ag + k0, AsW);
        gl2lds16(Ag + (long)64 * K + k0, AsW2);
        gl2lds16(Bg + k0, BsW);
        gl2lds16(Bg + (long)64 * K + k0, BsW2);
        __syncthreads();
        const int qk = (lane >> 4) * 8;
        const int mr = lane & 15;
        bf16x8 af[4], bfr[4];
#pragma unroll
        for (int i = 0; i < 4; i++) af[i]  = *(const bf16x8*)(&As[wm + i * 16 + mr][qk]);
#pragma unroll
        for (int j = 0; j < 4; j++) bfr[j] = *(const bf16x8*)(&Bs[wn + j * 16 + mr][qk]);
#pragma unroll
        for (int i = 0; i < 4; i++)
#pragma unroll
            for (int j = 0; j < 4; j++)
                acc[i][j] = __builtin_amdgcn_mfma_f32_16x16x32_bf16(af[i], bfr[j], acc[i][j], 0, 0, 0);
        __syncthreads();
    }

    const int cr = (lane >> 4) * 4;
    const int cc = lane & 15;
#pragma unroll
    for (int i = 0; i < 4; i++) {
#pragma unroll
        for (int j = 0; j < 4; j++) {
            const long m = m0 + wm + i * 16 + cr;
            const long n = n0 + wn + j * 16 + cc;
            if (F32OUT) {
                float* C = (float*)Cv;
#pragma unroll
                for (int r = 0; r < 4; r++) C[(m + r) * ldc + n] = acc[i][j][r];
            } else {
                u16* C = (u16*)Cv;
#pragma unroll
                for (int r = 0; r < 4; r++) C[(m + r) * ldc + n] = f2bf_h(acc[i][j][r]);
            }
        }
    }
}

// ---------------------------------------------------------------------------
// Fused: in-place L2-normalize q (x 1/16) and k per head; beta & dec per head.
// ---------------------------------------------------------------------------
__global__ __launch_bounds__(1024) void norm_beta_kernel(
    const u16* __restrict__ xb, u16* __restrict__ Y,
    const float* __restrict__ Wb, const float* __restrict__ Wa,
    const float* __restrict__ A_log, const float* __restrict__ dt_bias,
    float* __restrict__ beta, float* __restrict__ dec) {
    const long row = blockIdx.x;
    const int c = threadIdx.x;
    const int h = c >> 8;
    float qv = bf2f(Y[row * 3072 + c]);
    float kv = bf2f(Y[row * 3072 + 1024 + c]);
    float xv = bf2f(xb[row * 1024 + c]);
    float vals[10];
    vals[0] = qv * qv;
    vals[1] = kv * kv;
#pragma unroll
    for (int hh = 0; hh < 4; hh++) vals[2 + hh] = xv * Wb[c * 4 + hh];
#pragma unroll
    for (int hh = 0; hh < 4; hh++) vals[6 + hh] = xv * Wa[c * 4 + hh];
#pragma unroll
    for (int i = 0; i < 10; i++)
        for (int off = 32; off; off >>= 1) vals[i] += __shfl_xor(vals[i], off, 64);

    __shared__ float wred[16][10];
    __shared__ float sQ[4], sK[4];
    const int w = c >> 6;
    if ((c & 63) == 0) {
#pragma unroll
        for (int i = 0; i < 10; i++) wred[w][i] = vals[i];
    }
    __syncthreads();
    if (c < 4) {
        float s = wred[c * 4 + 0][0] + wred[c * 4 + 1][0] + wred[c * 4 + 2][0] + wred[c * 4 + 3][0];
        sQ[c] = rsqrtf(s + 1e-6f) * 0.0625f;
    } else if (c < 8) {
        int hh = c - 4;
        float s = wred[hh * 4 + 0][1] + wred[hh * 4 + 1][1] + wred[hh * 4 + 2][1] + wred[hh * 4 + 3][1];
        sK[hh] = rsqrtf(s + 1e-6f);
    } else if (c < 12) {
        int hh = c - 8;
        float s = 0.f;
        for (int ww = 0; ww < 16; ww++) s += wred[ww][2 + hh];
        beta[row * 4 + hh] = 1.f / (1.f + expf(-s));
    } else if (c < 16) {
        int hh = c - 12;
        float s = 0.f;
        for (int ww = 0; ww < 16; ww++) s += wred[ww][6 + hh];
        float z = s + dt_bias[hh];
        float sp = (z > 0.f) ? (z + log1pf(expf(-z))) : log1pf(expf(z));
        dec[row * 4 + hh] = expf(-expf(A_log[hh]) * sp);
    }
    __syncthreads();
    Y[row * 3072 + c]        = f2bf_h(qv * sQ[h]);
    Y[row * 3072 + 1024 + c] = f2bf_h(kv * sK[h]);
}

// ---------------------------------------------------------------------------
// PASS A (chunk-parallel prep). Unchanged from R6.
// ---------------------------------------------------------------------------
__global__ __launch_bounds__(256) void prep_kernel(const u16* __restrict__ Y,
                                                   const float* __restrict__ beta,
                                                   const float* __restrict__ dec,
                                                   u16* __restrict__ Tg,
                                                   u16* __restrict__ Mg,
                                                   float* __restrict__ sfg) {
    __shared__ __attribute__((aligned(16))) u16 lds[38400];
    __shared__ float sf[320];
    u16* KS  = lds;            // 64 x 264
    u16* QS  = lds + 16896;    // 64 x 264
    u16* AM  = lds + 33792;    // 64 x 72
    u16* Tm  = lds;            // overlays after G phase
    u16* AMT = lds + 4608;
    u16* MP  = lds + 9216;
    u16* MPT = lds + 13824;

    const int bx = blockIdx.x;
    const int bh = bx >> 6, c = bx & 63;
    const int b = bh >> 2, h = bh & 3;
    const int tid = threadIdx.x, lane = tid & 63, wv = tid >> 6;
    const int quad = lane >> 4, l15 = lane & 15;
    const int tld = tid >> 2, seg = tid & 3;
    const long bt0 = (long)b * 4096 + c * 64;
    u16* Tc = Tg + (size_t)(bh * 64 + c) * 4096;
    u16* Mc = Mg + (size_t)(bh * 64 + c) * 4096;
    const f32x4 z4 = {0.f, 0.f, 0.f, 0.f};

    {
        const long rb = (bt0 + tld) * 3072 + h * 256 + seg * 64;
#pragma unroll
        for (int i = 0; i < 8; i++) {
            *(u16x8*)&KS[tld * 264 + seg * 64 + i * 8] = *(const u16x8*)&Y[rb + 1024 + i * 8];
            *(u16x8*)&QS[tld * 264 + seg * 64 + i * 8] = *(const u16x8*)&Y[rb + i * 8];
        }
    }
    if (wv == 0) {
        float d   = dec [(bt0 + lane) * 4 + h];
        float bt_ = beta[(bt0 + lane) * 4 + h];
        float lg = log2f(fmaxf(d, 1e-30f));
#pragma unroll
        for (int off = 1; off < 64; off <<= 1) {
            float o = __shfl_up(lg, off, 64);
            if (lane >= off) lg += o;
        }
        sf[lane] = lg; sf[192 + lane] = bt_;
        float lgL = __shfl(lg, 63, 64);
        float g = exp2f(lg);
        float* sfc = sfg + (size_t)(bh * 64 + c) * 256;
        sfc[lane]       = g;
        sfc[64 + lane]  = bt_ * g;
        sfc[128 + lane] = bt_;
        sfc[192 + lane] = exp2f(lgL - lg);
    }
    __syncthreads();   // B1

    {
        const u16* Ab = (wv < 2) ? KS : QS;
        const int mb = (wv & 1) * 32;
        f32x4 g[2][4];
#pragma unroll
        for (int mi = 0; mi < 2; mi++)
#pragma unroll
            for (int sj = 0; sj < 4; sj++) g[mi][sj] = z4;
#pragma unroll 2
        for (int k0 = 0; k0 < 256; k0 += 32) {
            bf16x8 bfr[4];
#pragma unroll
            for (int sj = 0; sj < 4; sj++) bfr[sj] = ldfrag(KS, 264, sj * 16, k0, lane);
#pragma unroll
            for (int mi = 0; mi < 2; mi++) {
                bf16x8 af = ldfrag(Ab, 264, mb + mi * 16, k0, lane);
#pragma unroll
                for (int sj = 0; sj < 4; sj++)
                    g[mi][sj] = __builtin_amdgcn_mfma_f32_16x16x32_bf16(af, bfr[sj], g[mi][sj], 0, 0, 0);
            }
        }
#pragma unroll
        for (int mi = 0; mi < 2; mi++)
#pragma unroll
            for (int sj = 0; sj < 4; sj++)
#pragma unroll
                for (int r = 0; r < 4; r++) {
                    const int t_ = mb + mi * 16 + quad * 4 + r, s_ = sj * 16 + l15;
                    if (wv < 2)
                        AM[t_ * 72 + s_] = (s_ < t_) ? f2bf_h(sf[192 + t_] * exp2f(sf[t_] - sf[s_]) * g[mi][sj][r]) : (u16)0;
                    else
                        Mc[t_ * 64 + s_] = (s_ <= t_) ? f2bf_h(exp2f(sf[t_] - sf[s_]) * g[mi][sj][r]) : (u16)0;
                }
    }
    __syncthreads();   // B2

    {
        const int t_ = tid >> 2;
#pragma unroll
        for (int i = 0; i < 16; i++) {
            const int s_ = (tid & 3) * 16 + i;
            const u16 a = AM[t_ * 72 + s_];
            Tm[t_ * 72 + s_] = (t_ == s_) ? (u16)0x3F80 : (u16)(a ^ 0x8000);
            AMT[s_ * 72 + t_] = a;
        }
    }
    __syncthreads();   // B3

    {
        f32x4 sq[4];
#pragma unroll
        for (int sj = 0; sj < 4; sj++) sq[sj] = z4;
#pragma unroll
        for (int k0 = 0; k0 < 64; k0 += 32) {
            bf16x8 a = ldfrag(AM, 72, 16 * wv, k0, lane);
#pragma unroll
            for (int sj = 0; sj < 4; sj++) {
                bf16x8 bb = ldfrag(AMT, 72, sj * 16, k0, lane);
                sq[sj] = __builtin_amdgcn_mfma_f32_16x16x32_bf16(a, bb, sq[sj], 0, 0, 0);
            }
        }
#pragma unroll
        for (int sj = 0; sj < 4; sj++)
#pragma unroll
            for (int r = 0; r < 4; r++) {
                const int t_ = 16 * wv + quad * 4 + r, s_ = sj * 16 + l15;
                const u16 vbf = f2bf_h(sq[sj][r]);
                MP[t_ * 72 + s_] = vbf;
                MPT[s_ * 72 + t_] = vbf;
            }
        __syncthreads();   // B4
    }

#pragma unroll 1
    for (int jj = 0; jj < 5; jj++) {
        const bool last = (jj == 4);
        f32x4 pp[4], sq[4];
#pragma unroll
        for (int sj = 0; sj < 4; sj++) {
            sq[sj] = z4;
#pragma unroll
            for (int r = 0; r < 4; r++)
                pp[sj][r] = bf2f(Tm[(16 * wv + quad * 4 + r) * 72 + sj * 16 + l15]);
        }
#pragma unroll
        for (int k0 = 0; k0 < 64; k0 += 32) {
            bf16x8 at = ldfrag(Tm, 72, 16 * wv, k0, lane);
            bf16x8 am = ldfrag(MP, 72, 16 * wv, k0, lane);
#pragma unroll
            for (int sj = 0; sj < 4; sj++) {
                bf16x8 bb = ldfrag(MPT, 72, sj * 16, k0, lane);
                pp[sj] = __builtin_amdgcn_mfma_f32_16x16x32_bf16(at, bb, pp[sj], 0, 0, 0);
                if (!last) sq[sj] = __builtin_amdgcn_mfma_f32_16x16x32_bf16(am, bb, sq[sj], 0, 0, 0);
            }
        }
        __syncthreads();
#pragma unroll
        for (int sj = 0; sj < 4; sj++)
#pragma unroll
            for (int r = 0; r < 4; r++) {
                const int t_ = 16 * wv + quad * 4 + r, s_ = sj * 16 + l15;
                Tm[t_ * 72 + s_] = f2bf_h(pp[sj][r]);
                if (!last) {
                    const u16 vbf = f2bf_h(sq[sj][r]);
                    MP[t_ * 72 + s_] = vbf;
                    MPT[s_ * 72 + t_] = vbf;
                }
            }
        __syncthreads();
    }

    {
        const int t_ = tid >> 2;
#pragma unroll
        for (int i = 0; i < 16; i++) {
            const int s_ = (tid & 3) * 16 + i;
            Tc[t_ * 64 + s_] = Tm[t_ * 72 + s_];
        }
    }
}

// ---------------------------------------------------------------------------
// PASS B fused with the gate GEMM (R7):
//  blocks 0..63   : sequential scan (R4/R6 code, unchanged; 64 CUs)
//  blocks 64..575 : gate GEMM x@WgT -> GX, two 128^2 tiles per 512-thr block,
//                   riding the ~192 CUs the scan leaves idle. No cross-path
//                   dependency; any dispatch interleave is correct.
// Shared LDS arena carved per path (scan 98.4 KB / gemm 18.4 KB union).
// ---------------------------------------------------------------------------
struct Frag { bf16x8 f[8]; };
#define LDA 40

__global__ __launch_bounds__(512, 2) void scan_gate_kernel(
    const u16* __restrict__ Y, const float* __restrict__ sfg,
    const u16* __restrict__ Tg, const u16* __restrict__ Mg,
    u16* __restrict__ Ob,
    const float* __restrict__ x, const u16* __restrict__ WgT,
    u16* __restrict__ GX) {
    __shared__ __attribute__((aligned(16))) u16 smem[49184];

    const int tid = threadIdx.x;

    if (blockIdx.x >= 64) {
        // ================= gate GEMM path: two 128^2 tiles =================
        u16* As = smem + (tid >> 8) * 9216;            // [128][LDA=40]
        u16* Bs = As + 5120;                            // [128][32]
        const int t256 = tid & 255;
        const int lane = t256 & 63;
        const int wave = t256 >> 6;
        const int wm   = (wave >> 1) * 64;
        const int wn   = (wave & 1) * 64;
        const int tl   = (blockIdx.x - 64) * 2 + (tid >> 8);   // 0..1023
        const long m0  = (long)(tl >> 3) * 128;
        const long n0  = (long)(tl & 7) * 128;
        const int K = 1024, ldc = 1024;

        const f32x4 zero = {0.f, 0.f, 0.f, 0.f};
        f32x4 acc[4][4];
#pragma unroll
        for (int i = 0; i < 4; i++)
#pragma unroll
            for (int j = 0; j < 4; j++) acc[i][j] = zero;

        const int r0 = t256 >> 2;
        const int c0 = (t256 & 3) * 8;
        const float* Ag = x + (m0 + r0) * K + c0;
        const u16* Bg = WgT + (n0 + r0) * K + c0;
        u16* BsW  = Bs + wave * 16 * 32;
        u16* BsW2 = Bs + (wave * 16 + 64) * 32;

        for (int k0 = 0; k0 < K; k0 += 32) {
            gl2lds16(Bg + k0, BsW);
            gl2lds16(Bg + (long)64 * K + k0, BsW2);
            f32x4 af0 = *(const f32x4*)(Ag + k0);
            f32x4 af1 = *(const f32x4*)(Ag + k0 + 4);
            f32x4 ag0 = *(const f32x4*)(Ag + (long)64 * K + k0);
            f32x4 ag1 = *(const f32x4*)(Ag + (long)64 * K + k0 + 4);
            u16x8 a0, a1;
#pragma unroll
            for (int r = 0; r < 4; r++) {
                a0[r] = f2bf_h(af0[r]); a0[r + 4] = f2bf_h(af1[r]);
                a1[r] = f2bf_h(ag0[r]); a1[r + 4] = f2bf_h(ag1[r]);
            }
            *(u16x8*)(As + r0 * LDA + c0)        = a0;
            *(u16x8*)(As + (r0 + 64) * LDA + c0) = a1;
            __syncthreads();
            const int qk = (lane >> 4) * 8;
            const int mr = lane & 15;
            bf16x8 af[4], bfr[4];
#pragma unroll
            for (int i = 0; i < 4; i++) af[i]  = *(const bf16x8*)(As + (wm + i * 16 + mr) * LDA + qk);
#pragma unroll
            for (int j = 0; j < 4; j++) bfr[j] = *(const bf16x8*)(Bs + (wn + j * 16 + mr) * 32 + qk);
#pragma unroll
            for (int i = 0; i < 4; i++)
#pragma unroll
                for (int j = 0; j < 4; j++)
                    acc[i][j] = __builtin_amdgcn_mfma_f32_16x16x32_bf16(af[i], bfr[j], acc[i][j], 0, 0, 0);
            __syncthreads();
        }

        const int cr = (lane >> 4) * 4;
        const int cc = lane & 15;
#pragma unroll
        for (int i = 0; i < 4; i++) {
#pragma unroll
            for (int j = 0; j < 4; j++) {
                const long m = m0 + wm + i * 16 + cr;
                const long n = n0 + wn + j * 16 + cc;
#pragma unroll
                for (int r = 0; r < 4; r++) GX[(m + r) * ldc + n] = f2bf_h(acc[i][j][r]);
            }
        }
        return;
    }

    // ====================== scan path (unchanged R6) ======================
    u16* KT   = smem;              // 4*4616
    u16* ST   = smem + 18464;      // 64*264
    u16* RHST = smem + 35360;      // 64*72
    u16* UTp  = smem + 39968;      // 64*72
    u16* UTk  = smem + 44576;      // 64*72

    const int px = blockIdx.x;
    const int bh = (px & 7) | ((px >> 5) << 3);
    const int dvs = (px >> 3) & 3;
    const int b = bh >> 2, h = bh & 3;
    const int lane = tid & 63, wv = tid >> 6;
    const int wq = wv & 3;
    const int isQ = wv >> 2;
    const int quad = lane >> 4, l15 = lane & 15;
    const int tW = 16 * wq + l15;
    const int tph = 16 * ((wq + quad) & 3) + l15;
    int toff[4];
#pragma unroll
    for (int j = 0; j < 4; j++) toff[j] = ((((j << 1) + (l15 >> 3)) & 3) << 4);
    const f32x4 z4 = {0.f, 0.f, 0.f, 0.f};

    f32x4 Sacc[2][4];
#pragma unroll
    for (int i = 0; i < 2; i++)
#pragma unroll
        for (int j = 0; j < 4; j++) Sacc[i][j] = z4;
    for (int i = tid; i < 64 * 264; i += 512) ST[i] = 0;
    __syncthreads();

    const long roleOff = isQ ? 0 : 1024;
    Frag F0, F1;
    {
        const u16* Pg = Y + ((long)b * 4096) * 3072 + roleOff + h * 256;
#pragma unroll
        for (int i = 0; i < 8; i++) F0.f[i] = ldfrag(Pg, 3072, 16 * wq, i * 32, lane);
    }

    f32x4 oaccP[4];
#pragma unroll
    for (int j = 0; j < 4; j++) oaccP[j] = z4;
    bf16x8 amP0 = {}, amP1 = {};
    long obP = 0;
    int havePrev = 0;

    auto body = [&](Frag& cur, Frag& nxt, int c) {
        const long bt0 = (long)b * 4096 + (long)c * 64;
        const int cn = (c < 63) ? c + 1 : 63;

        {
            const u16* Pg = Y + ((long)b * 4096 + (long)cn * 64) * 3072 + roleOff + h * 256;
#pragma unroll
            for (int i = 0; i < 8; i++) nxt.f[i] = ldfrag(Pg, 3072, 16 * wq, i * 32, lane);
        }

        const u16* Tc = Tg + (size_t)(bh * 64 + c) * 4096;
        bf16x8 at0 = ldfrag(Tc, 64, 16 * wq, 0, lane);
        bf16x8 at1 = ldfrag(Tc, 64, 16 * wq, 32, lane);
        const float* sfc = sfg + (size_t)(bh * 64 + c) * 256;
        const float gam_l = sfc[tW];
        const float bg_l  = sfc[64 + tW];
        const float bet_l = sfc[128 + tW];
        const float ksc_l = sfc[192 + tW];
        const float gL    = sfc[63];

        u16x4 v4[4];
        if (!isQ) {
            const u16* Vr = Y + (bt0 + tW) * 3072 + 2048 + h * 256 + dvs * 64;
#pragma unroll
            for (int j = 0; j < 4; j++) v4[j] = *(const u16x4*)(Vr + j * 16 + quad * 4);
        } else {
            const u16* Mc = Mg + (size_t)(bh * 64 + c) * 4096;
            bf16x8 amN0 = ldfrag(Mc, 64, 16 * wq, 0, lane);
            bf16x8 amN1 = ldfrag(Mc, 64, 16 * wq, 32, lane);
            if (havePrev) {
#pragma unroll
                for (int sj = 0; sj < 4; sj++) {
                    bf16x8 ua0 = ldfrag(UTp, 72, sj * 16, 0, lane);
                    oaccP[sj] = __builtin_amdgcn_mfma_f32_16x16x32_bf16(ua0, amP0, oaccP[sj], 0, 0, 0);
                    bf16x8 ua1 = ldfrag(UTp, 72, sj * 16, 32, lane);
                    oaccP[sj] = __builtin_amdgcn_mfma_f32_16x16x32_bf16(ua1, amP1, oaccP[sj], 0, 0, 0);
                }
#pragma unroll
                for (int sj = 0; sj < 4; sj++) {
                    u16x4 o4;
#pragma unroll
                    for (int r = 0; r < 4; r++) o4[r] = f2bf_h(oaccP[sj][r]);
                    *(u16x4*)(Ob + obP + sj * 16 + quad * 4) = o4;
                }
            }
            amP0 = amN0; amP1 = amN1;
        }

        f32x4 p[4];
#pragma unroll
        for (int j = 0; j < 4; j++) p[j] = z4;
#pragma unroll
        for (int i = 0; i < 8; i++) {
            bf16x8 sfr[4];
#pragma unroll
            for (int j = 0; j < 4; j++) sfr[j] = ldfrag(ST, 264, j * 16, i * 32, lane);
#pragma unroll
            for (int j = 0; j < 4; j++)
                p[j] = __builtin_amdgcn_mfma_f32_16x16x32_bf16(sfr[j], cur.f[i], p[j], 0, 0, 0);
        }

        if (!isQ) {
#pragma unroll
            for (int i = 0; i < 8; i++) {
                const u16* src = (const u16*)&cur.f[i];
                u16* dst = KT + (i >> 1) * 4616 + ((i & 1) * 32 + quad * 8) * 72 + tph;
#pragma unroll
                for (int jj = 0; jj < 8; jj++) dst[jj * 72] = src[jj];
            }
#pragma unroll
            for (int j = 0; j < 4; j++)
#pragma unroll
                for (int r = 0; r < 4; r++) {
                    const int row = j * 16 + quad * 4 + r;
                    RHST[row * 72 + tW] = f2bf_h(bet_l * bf2f(v4[j][r]) - bg_l * p[j][r]);
                }
        } else {
#pragma unroll
            for (int j = 0; j < 4; j++)
#pragma unroll
                for (int r = 0; r < 4; r++) oaccP[j][r] = gam_l * p[j][r];
            obP = (bt0 + tW) * 1024 + h * 256 + (long)dvs * 64;
            havePrev = 1;
        }
        block_barrier();   // B2

        {
#pragma unroll
            for (int s2 = 0; s2 < 2; s2++) {
                const int sj = isQ * 2 + s2;
                f32x4 uu = z4;
                bf16x8 ra0 = ldfrag(RHST, 72, sj * 16, 0, lane);
                uu = __builtin_amdgcn_mfma_f32_16x16x32_bf16(ra0, at0, uu, 0, 0, 0);
                bf16x8 ra1 = ldfrag(RHST, 72, sj * 16, 32, lane);
                uu = __builtin_amdgcn_mfma_f32_16x16x32_bf16(ra1, at1, uu, 0, 0, 0);
#pragma unroll
                for (int r = 0; r < 4; r++) {
                    const int row = sj * 16 + quad * 4 + r;
                    UTp[row * 72 + tW] = f2bf_h(uu[r]);
                    UTk[row * 72 + tW] = f2bf_h(ksc_l * uu[r]);
                }
            }
        }
        block_barrier();   // B3

        {
#pragma unroll
            for (int i = 0; i < 2; i++)
#pragma unroll
                for (int j = 0; j < 4; j++) Sacc[i][j] *= gL;
            const u16* KTp = KT + wq * 4616;
#pragma unroll
            for (int k0 = 0; k0 < 64; k0 += 32) {
                bf16x8 au[2], bk[4];
#pragma unroll
                for (int i = 0; i < 2; i++) au[i] = ldfrag(UTk, 72, isQ * 32 + i * 16, k0, lane);
#pragma unroll
                for (int j = 0; j < 4; j++)
                    bk[j] = *(const bf16x8*)(KTp + (size_t)(j * 16 + l15) * 72 +
                                             ((k0 + quad * 8 + toff[j]) & 63));
#pragma unroll
                for (int i = 0; i < 2; i++)
#pragma unroll
                    for (int j = 0; j < 4; j++)
                        Sacc[i][j] = __builtin_amdgcn_mfma_f32_16x16x32_bf16(au[i], bk[j], Sacc[i][j], 0, 0, 0);
            }
#pragma unroll
            for (int i = 0; i < 2; i++)
#pragma unroll
                for (int j = 0; j < 4; j++)
#pragma unroll
                    for (int r = 0; r < 4; r++)
                        ST[(isQ * 32 + i * 16 + quad * 4 + r) * 264 + wq * 64 + j * 16 + l15] = f2bf_h(Sacc[i][j][r]);
        }
        block_barrier();   // B4
    };

#pragma unroll 1
    for (int c = 0; c < 64; c += 2) {
        body(F0, F1, c);
        body(F1, F0, c + 1);
    }

    if (isQ) {
#pragma unroll
        for (int sj = 0; sj < 4; sj++) {
            bf16x8 ua0 = ldfrag(UTp, 72, sj * 16, 0, lane);
            oaccP[sj] = __builtin_amdgcn_mfma_f32_16x16x32_bf16(ua0, amP0, oaccP[sj], 0, 0, 0);
            bf16x8 ua1 = ldfrag(UTp, 72, sj * 16, 32, lane);
            oaccP[sj] = __builtin_amdgcn_mfma_f32_16x16x32_bf16(ua1, amP1, oaccP[sj], 0, 0, 0);
        }
#pragma unroll
        for (int sj = 0; sj < 4; sj++) {
            u16x4 o4;
#pragma unroll
            for (int r = 0; r < 4; r++) o4[r] = f2bf_h(oaccP[sj][r]);
            *(u16x4*)(Ob + obP + sj * 16 + quad * 4) = o4;
        }
    }
}

// ---------------------------------------------------------------------------
// Gated RMSNorm + SiLU; reads O and gate(GX), writes og IN PLACE into GX.
// ---------------------------------------------------------------------------
__global__ __launch_bounds__(256) void gate_norm_kernel(const u16* __restrict__ O,
                                                        u16* __restrict__ G,
                                                        const float* __restrict__ norm_w) {
    const long row = blockIdx.x >> 2;
    const int h = blockIdx.x & 3;
    const int dv = threadIdx.x;
    const long idx = row * 1024 + h * 256 + dv;
    float o = bf2f(O[idx]);
    float s = o * o;
#pragma unroll
    for (int off = 32; off; off >>= 1) s += __shfl_xor(s, off, 64);
    __shared__ float wsum[4];
    if ((dv & 63) == 0) wsum[dv >> 6] = s;
    __syncthreads();
    const float tot = wsum[0] + wsum[1] + wsum[2] + wsum[3];
    const float r = rsqrtf(tot * (1.f / 256.f) + 1e-5f);
    const float g = bf2f(G[idx]);
    const float val = o * r * norm_w[dv] * (g / (1.f + expf(-g)));
    G[idx] = f2bf_h(val);
}

// ---------------------------------------------------------------------------
extern "C" void kernel_launch(void* const* d_in, const int* in_sizes, int n_in,
                              void* d_out, int out_size, void* d_ws, size_t ws_size,
                              hipStream_t stream) {
    const float* x       = (const float*)d_in[0];
    const float* Wq      = (const float*)d_in[1];
    const float* Wk      = (const float*)d_in[2];
    const float* Wv      = (const float*)d_in[3];
    const float* Wb      = (const float*)d_in[4];
    const float* Wa      = (const float*)d_in[5];
    const float* A_log   = (const float*)d_in[6];
    const float* dt_bias = (const float*)d_in[7];
    const float* Wg      = (const float*)d_in[8];
    const float* norm_w  = (const float*)d_in[9];
    const float* Wo      = (const float*)d_in[10];

    // workspace: ~202 MB (R6's 179 MB + new 33.6 MB GX region for the
    // co-run gate output).
    char* p = (char*)d_ws;
    u16*   WT   = (u16*)p;   p += (size_t)5120 * 1024 * 2;   // WqT|WkT|WvT|WgT|WoT bf16
    u16*   Y    = (u16*)p;   p += (size_t)16384 * 3072 * 2;  // q|k|v bf16
    u16*   G    = (u16*)p;   p += (size_t)16384 * 1024 * 2;  // T|M (prep+scan)
    u16*   XO   = (u16*)p;   p += (size_t)16384 * 1024 * 2;  // xb (early), O (scan output)
    float* beta = (float*)p; p += (size_t)16384 * 4 * 4;
    float* dec  = (float*)p; p += (size_t)16384 * 4 * 4;
    u16*   GX   = (u16*)p;   p += (size_t)16384 * 1024 * 2;  // gate, then og

    u16* Tg = G;                                  // 8.4 MB
    u16* Mg = G + (size_t)1024 * 4096;            // 8.4 MB
    float* sfg = (float*)WT;                      // overlays dead WqT after QKV

    cvt_kernel<<<16384, 256, 0, stream>>>(x, XO);

    transpose5_kernel<<<dim3(32, 32, 5), dim3(32, 8), 0, stream>>>(
        Wq, Wk, Wv, Wg, Wo, WT);

    // Y = xb @ [Wq|Wk|Wv]   (M=16384, N=3072, K=1024; bf16 A, gll staging)
    gemm_kernel<0><<<dim3(3072 / 128, 16384 / 128), 256, 0, stream>>>(
        XO, WT, (void*)Y, 16384, 3072, 1024, 3072);

    norm_beta_kernel<<<16384, 1024, 0, stream>>>(XO, Y, Wb, Wa, A_log, dt_bias, beta, dec);

    prep_kernel<<<1024, 256, 0, stream>>>(Y, beta, dec, Tg, Mg, sfg);

    // fused: scan (blocks 0-63) + gate GEMM x@WgT -> GX (blocks 64-575)
    scan_gate_kernel<<<576, 512, 0, stream>>>(
        Y, sfg, Tg, Mg, XO, x, WT + (size_t)3072 * 1024, GX);

    gate_norm_kernel<<<16384 * 4, 256, 0, stream>>>(XO, GX, norm_w);

    // out = og @ Wo   (fp32 out)
    gemm_kernel<1><<<dim3(1024 / 128, 16384 / 128), 256, 0, stream>>>(
        GX, WT + (size_t)4096 * 1024, d_out, 16384, 1024, 1024, 1024);
}

// Round 8
// 861.029 us; speedup vs baseline: 1.2190x; 1.0439x over previous
//
#include <hip/hip_runtime.h>

typedef unsigned short u16;
typedef __bf16 bf16x8 __attribute__((ext_vector_type(8)));
typedef u16 u16x8 __attribute__((ext_vector_type(8)));
typedef u16 u16x4 __attribute__((ext_vector_type(4)));
typedef float f32x4 __attribute__((ext_vector_type(4)));

__device__ __forceinline__ float bf2f(u16 v) {
    union { unsigned u; float f; } c; c.u = ((unsigned)v) << 16; return c.f;
}
// HW RNE f32->bf16 (single v_cvt)
__device__ __forceinline__ u16 f2bf_h(float f) {
    __bf16 h = (__bf16)f;
    union { __bf16 h; u16 u; } c; c.h = h; return c.u;
}

// MFMA fragment load (works for LDS or global pointers): LEFT operand from
// [m][k] row-major, or RIGHT operand from [n][k] row-major.
__device__ __forceinline__ bf16x8 ldfrag(const u16* base, int stride, int row0, int k0, int lane) {
    return *(const bf16x8*)(base + (size_t)(row0 + (lane & 15)) * stride + k0 + (lane >> 4) * 8);
}

// Raw workgroup barrier: commits LDS (lgkmcnt only) but does NOT drain vmcnt.
__device__ __forceinline__ void block_barrier() {
    __builtin_amdgcn_sched_barrier(0);
    asm volatile("s_waitcnt lgkmcnt(0)");
    __builtin_amdgcn_s_barrier();
    __builtin_amdgcn_sched_barrier(0);
}

// async global->LDS, 16 B per lane. LDS dest must be wave-uniform base.
__device__ __forceinline__ void gl2lds16(const void* g, void* l) {
    __builtin_amdgcn_global_load_lds(
        (const __attribute__((address_space(1))) unsigned int*)g,
        (__attribute__((address_space(3))) unsigned int*)l, 16, 0, 0);
}

// ---------------------------------------------------------------------------
// R8: merged prologue -- cvt (x->bf16) + 5 weight transposes + WbaT staging
// in ONE launch. WbaT rows: 0-3 = Wb^T, 4-7 = (bf16 hi of Wa)^T,
// 8-11 = (lo residual of Wa)^T; rows 12-127 garbage (outputs never read).
// ---------------------------------------------------------------------------
__global__ __launch_bounds__(256) void prep0_kernel(
    const float* __restrict__ x, u16* __restrict__ XO,
    const float* __restrict__ Wq, const float* __restrict__ Wk,
    const float* __restrict__ Wv, const float* __restrict__ Wg,
    const float* __restrict__ Wo, u16* __restrict__ WT,
    const float* __restrict__ Wb, const float* __restrict__ Wa,
    u16* __restrict__ WbaT) {
    __shared__ float tile[32][33];
    const int bx = blockIdx.x, tid = threadIdx.x;

    if (bx < 16384) {                       // ---- cvt path ----
        const long i = ((long)bx * 256 + tid) * 4;
        f32x4 v = *(const f32x4*)(x + i);
        u16x4 o;
#pragma unroll
        for (int r = 0; r < 4; r++) o[r] = f2bf_h(v[r]);
        *(u16x4*)(XO + i) = o;
        return;
    }
    if (bx < 21504) {                       // ---- transpose path ----
        const int t = bx - 16384;
        const int z = t >> 10, r = t & 1023;
        const float* src = (z == 0) ? Wq : (z == 1) ? Wk : (z == 2) ? Wv : (z == 3) ? Wg : Wo;
        u16* dst = WT + (size_t)z * 1024 * 1024;
        const int n0 = (r & 31) * 32, k0 = (r >> 5) * 32;
        const int tx = tid & 31, ty = tid >> 5;
#pragma unroll
        for (int i = 0; i < 32; i += 8)
            tile[ty + i][tx] = src[(long)(k0 + ty + i) * 1024 + n0 + tx];
        __syncthreads();
#pragma unroll
        for (int i = 0; i < 32; i += 8)
            dst[(long)(n0 + ty + i) * 1024 + k0 + tx] = f2bf_h(tile[tx][ty + i]);
        return;
    }
    // ---- WbaT path: 12 x 1024 elems ----
    const int t = (bx - 21504) * 256 + tid;  // 0..12287
    const int n = t >> 10, k = t & 1023;
    float v;
    if (n < 4)      v = Wb[k * 4 + n];
    else if (n < 8) v = Wa[k * 4 + (n - 4)];
    else { float w = Wa[k * 4 + (n - 8)]; v = w - bf2f(f2bf_h(w)); }
    WbaT[(size_t)n * 1024 + k] = f2bf_h(v);
}

// ---------------------------------------------------------------------------
// QKV GEMM + preBA tile: grid (25, 128). Tiles 0-23: Y = xb @ [Wq|Wk|Wv]
// (bf16 out). Tile 24: preBA = xb @ [Wb|Wa_hi|Wa_lo] (fp32 out, ldc 128).
// m97-structure gll staging (R6/R7 winner).
// ---------------------------------------------------------------------------
__global__ __launch_bounds__(256) void qkv_kernel(const u16* __restrict__ A,
                                                  const u16* __restrict__ WTb,
                                                  const u16* __restrict__ WbaT,
                                                  u16* __restrict__ Y,
                                                  float* __restrict__ preBA) {
    __shared__ __attribute__((aligned(16))) u16 As[128][32];
    __shared__ __attribute__((aligned(16))) u16 Bs[128][32];
    const int tid  = threadIdx.x;
    const int lane = tid & 63;
    const int wave = tid >> 6;
    const int wm   = (wave >> 1) * 64;
    const int wn   = (wave & 1) * 64;
    const int isBA = (blockIdx.x == 24);
    const long m0  = (long)blockIdx.y * 128;
    const long n0  = isBA ? 0 : (long)blockIdx.x * 128;
    const u16* BT  = isBA ? WbaT : WTb;
    const int K = 1024;

    const f32x4 zero = {0.f, 0.f, 0.f, 0.f};
    f32x4 acc[4][4];
#pragma unroll
    for (int i = 0; i < 4; i++)
#pragma unroll
        for (int j = 0; j < 4; j++) acc[i][j] = zero;

    const int r0 = tid >> 2;
    const int c0 = (tid & 3) * 8;
    const u16* Ag = A + (m0 + r0) * K + c0;
    const u16* Bg = BT + (n0 + r0) * K + c0;
    u16* AsW  = &As[wave * 16][0];
    u16* AsW2 = &As[wave * 16 + 64][0];
    u16* BsW  = &Bs[wave * 16][0];
    u16* BsW2 = &Bs[wave * 16 + 64][0];

    for (int k0 = 0; k0 < K; k0 += 32) {
        gl2lds16(Ag + k0, AsW);
        gl2lds16(Ag + (long)64 * K + k0, AsW2);
        gl2lds16(Bg + k0, BsW);
        gl2lds16(Bg + (long)64 * K + k0, BsW2);
        __syncthreads();
        const int qk = (lane >> 4) * 8;
        const int mr = lane & 15;
        bf16x8 af[4], bfr[4];
#pragma unroll
        for (int i = 0; i < 4; i++) af[i]  = *(const bf16x8*)(&As[wm + i * 16 + mr][qk]);
#pragma unroll
        for (int j = 0; j < 4; j++) bfr[j] = *(const bf16x8*)(&Bs[wn + j * 16 + mr][qk]);
#pragma unroll
        for (int i = 0; i < 4; i++)
#pragma unroll
            for (int j = 0; j < 4; j++)
                acc[i][j] = __builtin_amdgcn_mfma_f32_16x16x32_bf16(af[i], bfr[j], acc[i][j], 0, 0, 0);
        __syncthreads();
    }

    const int cr = (lane >> 4) * 4;
    const int cc = lane & 15;
#pragma unroll
    for (int i = 0; i < 4; i++) {
#pragma unroll
        for (int j = 0; j < 4; j++) {
            const long m = m0 + wm + i * 16 + cr;
            const long n = n0 + wn + j * 16 + cc;
            if (isBA) {
#pragma unroll
                for (int r = 0; r < 4; r++) preBA[(m + r) * 128 + n] = acc[i][j][r];
            } else {
#pragma unroll
                for (int r = 0; r < 4; r++) Y[(m + r) * 3072 + n] = f2bf_h(acc[i][j][r]);
            }
        }
    }
}

// ---------------------------------------------------------------------------
// MFMA GEMM (bf16 A/B, gll staging) -- used for the out GEMM.
// ---------------------------------------------------------------------------
template <int F32OUT>
__global__ __launch_bounds__(256) void gemm_kernel(const u16* __restrict__ A,
                                                   const u16* __restrict__ BT,
                                                   void* __restrict__ Cv,
                                                   int M, int N, int K, int ldc) {
    __shared__ __attribute__((aligned(16))) u16 As[128][32];
    __shared__ __attribute__((aligned(16))) u16 Bs[128][32];
    const int tid  = threadIdx.x;
    const int lane = tid & 63;
    const int wave = tid >> 6;
    const int wm   = (wave >> 1) * 64;
    const int wn   = (wave & 1) * 64;
    const long m0  = (long)blockIdx.y * 128;
    const long n0  = (long)blockIdx.x * 128;

    const f32x4 zero = {0.f, 0.f, 0.f, 0.f};
    f32x4 acc[4][4];
#pragma unroll
    for (int i = 0; i < 4; i++)
#pragma unroll
        for (int j = 0; j < 4; j++) acc[i][j] = zero;

    const int r0 = tid >> 2;
    const int c0 = (tid & 3) * 8;
    const u16* Ag = A + (m0 + r0) * K + c0;
    const u16* Bg = BT + (n0 + r0) * K + c0;
    u16* AsW  = &As[wave * 16][0];
    u16* AsW2 = &As[wave * 16 + 64][0];
    u16* BsW  = &Bs[wave * 16][0];
    u16* BsW2 = &Bs[wave * 16 + 64][0];

    for (int k0 = 0; k0 < K; k0 += 32) {
        gl2lds16(Ag + k0, AsW);
        gl2lds16(Ag + (long)64 * K + k0, AsW2);
        gl2lds16(Bg + k0, BsW);
        gl2lds16(Bg + (long)64 * K + k0, BsW2);
        __syncthreads();
        const int qk = (lane >> 4) * 8;
        const int mr = lane & 15;
        bf16x8 af[4], bfr[4];
#pragma unroll
        for (int i = 0; i < 4; i++) af[i]  = *(const bf16x8*)(&As[wm + i * 16 + mr][qk]);
#pragma unroll
        for (int j = 0; j < 4; j++) bfr[j] = *(const bf16x8*)(&Bs[wn + j * 16 + mr][qk]);
#pragma unroll
        for (int i = 0; i < 4; i++)
#pragma unroll
            for (int j = 0; j < 4; j++)
                acc[i][j] = __builtin_amdgcn_mfma_f32_16x16x32_bf16(af[i], bfr[j], acc[i][j], 0, 0, 0);
        __syncthreads();
    }

    const int cr = (lane >> 4) * 4;
    const int cc = lane & 15;
#pragma unroll
    for (int i = 0; i < 4; i++) {
#pragma unroll
        for (int j = 0; j < 4; j++) {
            const long m = m0 + wm + i * 16 + cr;
            const long n = n0 + wn + j * 16 + cc;
            if (F32OUT) {
                float* C = (float*)Cv;
#pragma unroll
                for (int r = 0; r < 4; r++) C[(m + r) * ldc + n] = acc[i][j][r];
            } else {
                u16* C = (u16*)Cv;
#pragma unroll
                for (int r = 0; r < 4; r++) C[(m + r) * ldc + n] = f2bf_h(acc[i][j][r]);
            }
        }
    }
}

// ---------------------------------------------------------------------------
// R8 norm_beta: only q^2/k^2 reductions remain (2 instead of 10); beta/dec
// come from preBA (fp32 MFMA output; Wa in hi+lo bf16 pair for precision).
// ---------------------------------------------------------------------------
__global__ __launch_bounds__(1024) void norm_beta_kernel(
    u16* __restrict__ Y, const float* __restrict__ preBA,
    const float* __restrict__ A_log, const float* __restrict__ dt_bias,
    float* __restrict__ beta, float* __restrict__ dec) {
    const long row = blockIdx.x;
    const int c = threadIdx.x;
    const int h = c >> 8;
    float qv = bf2f(Y[row * 3072 + c]);
    float kv = bf2f(Y[row * 3072 + 1024 + c]);
    float s0 = qv * qv;
    float s1 = kv * kv;
#pragma unroll
    for (int off = 32; off; off >>= 1) {
        s0 += __shfl_xor(s0, off, 64);
        s1 += __shfl_xor(s1, off, 64);
    }
    __shared__ float wq_[16], wk_[16];
    __shared__ float sQ[4], sK[4];
    const int w = c >> 6;
    if ((c & 63) == 0) { wq_[w] = s0; wk_[w] = s1; }
    __syncthreads();
    if (c < 4) {
        float s = wq_[c * 4] + wq_[c * 4 + 1] + wq_[c * 4 + 2] + wq_[c * 4 + 3];
        sQ[c] = rsqrtf(s + 1e-6f) * 0.0625f;
    } else if (c < 8) {
        int hh = c - 4;
        float s = wk_[hh * 4] + wk_[hh * 4 + 1] + wk_[hh * 4 + 2] + wk_[hh * 4 + 3];
        sK[hh] = rsqrtf(s + 1e-6f);
    } else if (c < 12) {
        int hh = c - 8;
        float s = preBA[row * 128 + hh];
        beta[row * 4 + hh] = 1.f / (1.f + expf(-s));
    } else if (c < 16) {
        int hh = c - 12;
        float s = preBA[row * 128 + 4 + hh] + preBA[row * 128 + 8 + hh];
        float z = s + dt_bias[hh];
        float sp = (z > 0.f) ? (z + log1pf(expf(-z))) : log1pf(expf(z));
        dec[row * 4 + hh] = expf(-expf(A_log[hh]) * sp);
    }
    __syncthreads();
    Y[row * 3072 + c]        = f2bf_h(qv * sQ[h]);
    Y[row * 3072 + 1024 + c] = f2bf_h(kv * sK[h]);
}

// ---------------------------------------------------------------------------
// PASS A (chunk-parallel prep). Unchanged from R7.
// ---------------------------------------------------------------------------
__global__ __launch_bounds__(256) void prep_kernel(const u16* __restrict__ Y,
                                                   const float* __restrict__ beta,
                                                   const float* __restrict__ dec,
                                                   u16* __restrict__ Tg,
                                                   u16* __restrict__ Mg,
                                                   float* __restrict__ sfg) {
    __shared__ __attribute__((aligned(16))) u16 lds[38400];
    __shared__ float sf[320];
    u16* KS  = lds;            // 64 x 264
    u16* QS  = lds + 16896;    // 64 x 264
    u16* AM  = lds + 33792;    // 64 x 72
    u16* Tm  = lds;            // overlays after G phase
    u16* AMT = lds + 4608;
    u16* MP  = lds + 9216;
    u16* MPT = lds + 13824;

    const int bx = blockIdx.x;
    const int bh = bx >> 6, c = bx & 63;
    const int b = bh >> 2, h = bh & 3;
    const int tid = threadIdx.x, lane = tid & 63, wv = tid >> 6;
    const int quad = lane >> 4, l15 = lane & 15;
    const int tld = tid >> 2, seg = tid & 3;
    const long bt0 = (long)b * 4096 + c * 64;
    u16* Tc = Tg + (size_t)(bh * 64 + c) * 4096;
    u16* Mc = Mg + (size_t)(bh * 64 + c) * 4096;
    const f32x4 z4 = {0.f, 0.f, 0.f, 0.f};

    {
        const long rb = (bt0 + tld) * 3072 + h * 256 + seg * 64;
#pragma unroll
        for (int i = 0; i < 8; i++) {
            *(u16x8*)&KS[tld * 264 + seg * 64 + i * 8] = *(const u16x8*)&Y[rb + 1024 + i * 8];
            *(u16x8*)&QS[tld * 264 + seg * 64 + i * 8] = *(const u16x8*)&Y[rb + i * 8];
        }
    }
    if (wv == 0) {
        float d   = dec [(bt0 + lane) * 4 + h];
        float bt_ = beta[(bt0 + lane) * 4 + h];
        float lg = log2f(fmaxf(d, 1e-30f));
#pragma unroll
        for (int off = 1; off < 64; off <<= 1) {
            float o = __shfl_up(lg, off, 64);
            if (lane >= off) lg += o;
        }
        sf[lane] = lg; sf[192 + lane] = bt_;
        float lgL = __shfl(lg, 63, 64);
        float g = exp2f(lg);
        float* sfc = sfg + (size_t)(bh * 64 + c) * 256;
        sfc[lane]       = g;
        sfc[64 + lane]  = bt_ * g;
        sfc[128 + lane] = bt_;
        sfc[192 + lane] = exp2f(lgL - lg);
    }
    __syncthreads();   // B1

    {
        const u16* Ab = (wv < 2) ? KS : QS;
        const int mb = (wv & 1) * 32;
        f32x4 g[2][4];
#pragma unroll
        for (int mi = 0; mi < 2; mi++)
#pragma unroll
            for (int sj = 0; sj < 4; sj++) g[mi][sj] = z4;
#pragma unroll 2
        for (int k0 = 0; k0 < 256; k0 += 32) {
            bf16x8 bfr[4];
#pragma unroll
            for (int sj = 0; sj < 4; sj++) bfr[sj] = ldfrag(KS, 264, sj * 16, k0, lane);
#pragma unroll
            for (int mi = 0; mi < 2; mi++) {
                bf16x8 af = ldfrag(Ab, 264, mb + mi * 16, k0, lane);
#pragma unroll
                for (int sj = 0; sj < 4; sj++)
                    g[mi][sj] = __builtin_amdgcn_mfma_f32_16x16x32_bf16(af, bfr[sj], g[mi][sj], 0, 0, 0);
            }
        }
#pragma unroll
        for (int mi = 0; mi < 2; mi++)
#pragma unroll
            for (int sj = 0; sj < 4; sj++)
#pragma unroll
                for (int r = 0; r < 4; r++) {
                    const int t_ = mb + mi * 16 + quad * 4 + r, s_ = sj * 16 + l15;
                    if (wv < 2)
                        AM[t_ * 72 + s_] = (s_ < t_) ? f2bf_h(sf[192 + t_] * exp2f(sf[t_] - sf[s_]) * g[mi][sj][r]) : (u16)0;
                    else
                        Mc[t_ * 64 + s_] = (s_ <= t_) ? f2bf_h(exp2f(sf[t_] - sf[s_]) * g[mi][sj][r]) : (u16)0;
                }
    }
    __syncthreads();   // B2

    {
        const int t_ = tid >> 2;
#pragma unroll
        for (int i = 0; i < 16; i++) {
            const int s_ = (tid & 3) * 16 + i;
            const u16 a = AM[t_ * 72 + s_];
            Tm[t_ * 72 + s_] = (t_ == s_) ? (u16)0x3F80 : (u16)(a ^ 0x8000);
            AMT[s_ * 72 + t_] = a;
        }
    }
    __syncthreads();   // B3

    {
        f32x4 sq[4];
#pragma unroll
        for (int sj = 0; sj < 4; sj++) sq[sj] = z4;
#pragma unroll
        for (int k0 = 0; k0 < 64; k0 += 32) {
            bf16x8 a = ldfrag(AM, 72, 16 * wv, k0, lane);
#pragma unroll
            for (int sj = 0; sj < 4; sj++) {
                bf16x8 bb = ldfrag(AMT, 72, sj * 16, k0, lane);
                sq[sj] = __builtin_amdgcn_mfma_f32_16x16x32_bf16(a, bb, sq[sj], 0, 0, 0);
            }
        }
#pragma unroll
        for (int sj = 0; sj < 4; sj++)
#pragma unroll
            for (int r = 0; r < 4; r++) {
                const int t_ = 16 * wv + quad * 4 + r, s_ = sj * 16 + l15;
                const u16 vbf = f2bf_h(sq[sj][r]);
                MP[t_ * 72 + s_] = vbf;
                MPT[s_ * 72 + t_] = vbf;
            }
        __syncthreads();   // B4
    }

#pragma unroll 1
    for (int jj = 0; jj < 5; jj++) {
        const bool last = (jj == 4);
        f32x4 pp[4], sq[4];
#pragma unroll
        for (int sj = 0; sj < 4; sj++) {
            sq[sj] = z4;
#pragma unroll
            for (int r = 0; r < 4; r++)
                pp[sj][r] = bf2f(Tm[(16 * wv + quad * 4 + r) * 72 + sj * 16 + l15]);
        }
#pragma unroll
        for (int k0 = 0; k0 < 64; k0 += 32) {
            bf16x8 at = ldfrag(Tm, 72, 16 * wv, k0, lane);
            bf16x8 am = ldfrag(MP, 72, 16 * wv, k0, lane);
#pragma unroll
            for (int sj = 0; sj < 4; sj++) {
                bf16x8 bb = ldfrag(MPT, 72, sj * 16, k0, lane);
                pp[sj] = __builtin_amdgcn_mfma_f32_16x16x32_bf16(at, bb, pp[sj], 0, 0, 0);
                if (!last) sq[sj] = __builtin_amdgcn_mfma_f32_16x16x32_bf16(am, bb, sq[sj], 0, 0, 0);
            }
        }
        __syncthreads();
#pragma unroll
        for (int sj = 0; sj < 4; sj++)
#pragma unroll
            for (int r = 0; r < 4; r++) {
                const int t_ = 16 * wv + quad * 4 + r, s_ = sj * 16 + l15;
                Tm[t_ * 72 + s_] = f2bf_h(pp[sj][r]);
                if (!last) {
                    const u16 vbf = f2bf_h(sq[sj][r]);
                    MP[t_ * 72 + s_] = vbf;
                    MPT[s_ * 72 + t_] = vbf;
                }
            }
        __syncthreads();
    }

    {
        const int t_ = tid >> 2;
#pragma unroll
        for (int i = 0; i < 16; i++) {
            const int s_ = (tid & 3) * 16 + i;
            Tc[t_ * 64 + s_] = Tm[t_ * 72 + s_];
        }
    }
}

// ---------------------------------------------------------------------------
// PASS B fused with the gate GEMM. Unchanged from R7 (verified winner).
// ---------------------------------------------------------------------------
struct Frag { bf16x8 f[8]; };
#define LDA 40

__global__ __launch_bounds__(512, 2) void scan_gate_kernel(
    const u16* __restrict__ Y, const float* __restrict__ sfg,
    const u16* __restrict__ Tg, const u16* __restrict__ Mg,
    u16* __restrict__ Ob,
    const float* __restrict__ x, const u16* __restrict__ WgT,
    u16* __restrict__ GX) {
    __shared__ __attribute__((aligned(16))) u16 smem[49184];

    const int tid = threadIdx.x;

    if (blockIdx.x >= 64) {
        // ================= gate GEMM path: two 128^2 tiles =================
        u16* As = smem + (tid >> 8) * 9216;            // [128][LDA=40]
        u16* Bs = As + 5120;                            // [128][32]
        const int t256 = tid & 255;
        const int lane = t256 & 63;
        const int wave = t256 >> 6;
        const int wm   = (wave >> 1) * 64;
        const int wn   = (wave & 1) * 64;
        const int tl   = (blockIdx.x - 64) * 2 + (tid >> 8);   // 0..1023
        const long m0  = (long)(tl >> 3) * 128;
        const long n0  = (long)(tl & 7) * 128;
        const int K = 1024, ldc = 1024;

        const f32x4 zero = {0.f, 0.f, 0.f, 0.f};
        f32x4 acc[4][4];
#pragma unroll
        for (int i = 0; i < 4; i++)
#pragma unroll
            for (int j = 0; j < 4; j++) acc[i][j] = zero;

        const int r0 = t256 >> 2;
        const int c0 = (t256 & 3) * 8;
        const float* Ag = x + (m0 + r0) * K + c0;
        const u16* Bg = WgT + (n0 + r0) * K + c0;
        u16* BsW  = Bs + wave * 16 * 32;
        u16* BsW2 = Bs + (wave * 16 + 64) * 32;

        for (int k0 = 0; k0 < K; k0 += 32) {
            gl2lds16(Bg + k0, BsW);
            gl2lds16(Bg + (long)64 * K + k0, BsW2);
            f32x4 af0 = *(const f32x4*)(Ag + k0);
            f32x4 af1 = *(const f32x4*)(Ag + k0 + 4);
            f32x4 ag0 = *(const f32x4*)(Ag + (long)64 * K + k0);
            f32x4 ag1 = *(const f32x4*)(Ag + (long)64 * K + k0 + 4);
            u16x8 a0, a1;
#pragma unroll
            for (int r = 0; r < 4; r++) {
                a0[r] = f2bf_h(af0[r]); a0[r + 4] = f2bf_h(af1[r]);
                a1[r] = f2bf_h(ag0[r]); a1[r + 4] = f2bf_h(ag1[r]);
            }
            *(u16x8*)(As + r0 * LDA + c0)        = a0;
            *(u16x8*)(As + (r0 + 64) * LDA + c0) = a1;
            __syncthreads();
            const int qk = (lane >> 4) * 8;
            const int mr = lane & 15;
            bf16x8 af[4], bfr[4];
#pragma unroll
            for (int i = 0; i < 4; i++) af[i]  = *(const bf16x8*)(As + (wm + i * 16 + mr) * LDA + qk);
#pragma unroll
            for (int j = 0; j < 4; j++) bfr[j] = *(const bf16x8*)(Bs + (wn + j * 16 + mr) * 32 + qk);
#pragma unroll
            for (int i = 0; i < 4; i++)
#pragma unroll
                for (int j = 0; j < 4; j++)
                    acc[i][j] = __builtin_amdgcn_mfma_f32_16x16x32_bf16(af[i], bfr[j], acc[i][j], 0, 0, 0);
            __syncthreads();
        }

        const int cr = (lane >> 4) * 4;
        const int cc = lane & 15;
#pragma unroll
        for (int i = 0; i < 4; i++) {
#pragma unroll
            for (int j = 0; j < 4; j++) {
                const long m = m0 + wm + i * 16 + cr;
                const long n = n0 + wn + j * 16 + cc;
#pragma unroll
                for (int r = 0; r < 4; r++) GX[(m + r) * ldc + n] = f2bf_h(acc[i][j][r]);
            }
        }
        return;
    }

    // ====================== scan path (unchanged R6) ======================
    u16* KT   = smem;              // 4*4616
    u16* ST   = smem + 18464;      // 64*264
    u16* RHST = smem + 35360;      // 64*72
    u16* UTp  = smem + 39968;      // 64*72
    u16* UTk  = smem + 44576;      // 64*72

    const int px = blockIdx.x;
    const int bh = (px & 7) | ((px >> 5) << 3);
    const int dvs = (px >> 3) & 3;
    const int b = bh >> 2, h = bh & 3;
    const int lane = tid & 63, wv = tid >> 6;
    const int wq = wv & 3;
    const int isQ = wv >> 2;
    const int quad = lane >> 4, l15 = lane & 15;
    const int tW = 16 * wq + l15;
    const int tph = 16 * ((wq + quad) & 3) + l15;
    int toff[4];
#pragma unroll
    for (int j = 0; j < 4; j++) toff[j] = ((((j << 1) + (l15 >> 3)) & 3) << 4);
    const f32x4 z4 = {0.f, 0.f, 0.f, 0.f};

    f32x4 Sacc[2][4];
#pragma unroll
    for (int i = 0; i < 2; i++)
#pragma unroll
        for (int j = 0; j < 4; j++) Sacc[i][j] = z4;
    for (int i = tid; i < 64 * 264; i += 512) ST[i] = 0;
    __syncthreads();

    const long roleOff = isQ ? 0 : 1024;
    Frag F0, F1;
    {
        const u16* Pg = Y + ((long)b * 4096) * 3072 + roleOff + h * 256;
#pragma unroll
        for (int i = 0; i < 8; i++) F0.f[i] = ldfrag(Pg, 3072, 16 * wq, i * 32, lane);
    }

    f32x4 oaccP[4];
#pragma unroll
    for (int j = 0; j < 4; j++) oaccP[j] = z4;
    bf16x8 amP0 = {}, amP1 = {};
    long obP = 0;
    int havePrev = 0;

    auto body = [&](Frag& cur, Frag& nxt, int c) {
        const long bt0 = (long)b * 4096 + (long)c * 64;
        const int cn = (c < 63) ? c + 1 : 63;

        {
            const u16* Pg = Y + ((long)b * 4096 + (long)cn * 64) * 3072 + roleOff + h * 256;
#pragma unroll
            for (int i = 0; i < 8; i++) nxt.f[i] = ldfrag(Pg, 3072, 16 * wq, i * 32, lane);
        }

        const u16* Tc = Tg + (size_t)(bh * 64 + c) * 4096;
        bf16x8 at0 = ldfrag(Tc, 64, 16 * wq, 0, lane);
        bf16x8 at1 = ldfrag(Tc, 64, 16 * wq, 32, lane);
        const float* sfc = sfg + (size_t)(bh * 64 + c) * 256;
        const float gam_l = sfc[tW];
        const float bg_l  = sfc[64 + tW];
        const float bet_l = sfc[128 + tW];
        const float ksc_l = sfc[192 + tW];
        const float gL    = sfc[63];

        u16x4 v4[4];
        if (!isQ) {
            const u16* Vr = Y + (bt0 + tW) * 3072 + 2048 + h * 256 + dvs * 64;
#pragma unroll
            for (int j = 0; j < 4; j++) v4[j] = *(const u16x4*)(Vr + j * 16 + quad * 4);
        } else {
            const u16* Mc = Mg + (size_t)(bh * 64 + c) * 4096;
            bf16x8 amN0 = ldfrag(Mc, 64, 16 * wq, 0, lane);
            bf16x8 amN1 = ldfrag(Mc, 64, 16 * wq, 32, lane);
            if (havePrev) {
#pragma unroll
                for (int sj = 0; sj < 4; sj++) {
                    bf16x8 ua0 = ldfrag(UTp, 72, sj * 16, 0, lane);
                    oaccP[sj] = __builtin_amdgcn_mfma_f32_16x16x32_bf16(ua0, amP0, oaccP[sj], 0, 0, 0);
                    bf16x8 ua1 = ldfrag(UTp, 72, sj * 16, 32, lane);
                    oaccP[sj] = __builtin_amdgcn_mfma_f32_16x16x32_bf16(ua1, amP1, oaccP[sj], 0, 0, 0);
                }
#pragma unroll
                for (int sj = 0; sj < 4; sj++) {
                    u16x4 o4;
#pragma unroll
                    for (int r = 0; r < 4; r++) o4[r] = f2bf_h(oaccP[sj][r]);
                    *(u16x4*)(Ob + obP + sj * 16 + quad * 4) = o4;
                }
            }
            amP0 = amN0; amP1 = amN1;
        }

        f32x4 p[4];
#pragma unroll
        for (int j = 0; j < 4; j++) p[j] = z4;
#pragma unroll
        for (int i = 0; i < 8; i++) {
            bf16x8 sfr[4];
#pragma unroll
            for (int j = 0; j < 4; j++) sfr[j] = ldfrag(ST, 264, j * 16, i * 32, lane);
#pragma unroll
            for (int j = 0; j < 4; j++)
                p[j] = __builtin_amdgcn_mfma_f32_16x16x32_bf16(sfr[j], cur.f[i], p[j], 0, 0, 0);
        }

        if (!isQ) {
#pragma unroll
            for (int i = 0; i < 8; i++) {
                const u16* src = (const u16*)&cur.f[i];
                u16* dst = KT + (i >> 1) * 4616 + ((i & 1) * 32 + quad * 8) * 72 + tph;
#pragma unroll
                for (int jj = 0; jj < 8; jj++) dst[jj * 72] = src[jj];
            }
#pragma unroll
            for (int j = 0; j < 4; j++)
#pragma unroll
                for (int r = 0; r < 4; r++) {
                    const int row = j * 16 + quad * 4 + r;
                    RHST[row * 72 + tW] = f2bf_h(bet_l * bf2f(v4[j][r]) - bg_l * p[j][r]);
                }
        } else {
#pragma unroll
            for (int j = 0; j < 4; j++)
#pragma unroll
                for (int r = 0; r < 4; r++) oaccP[j][r] = gam_l * p[j][r];
            obP = (bt0 + tW) * 1024 + h * 256 + (long)dvs * 64;
            havePrev = 1;
        }
        block_barrier();   // B2

        {
#pragma unroll
            for (int s2 = 0; s2 < 2; s2++) {
                const int sj = isQ * 2 + s2;
                f32x4 uu = z4;
                bf16x8 ra0 = ldfrag(RHST, 72, sj * 16, 0, lane);
                uu = __builtin_amdgcn_mfma_f32_16x16x32_bf16(ra0, at0, uu, 0, 0, 0);
                bf16x8 ra1 = ldfrag(RHST, 72, sj * 16, 32, lane);
                uu = __builtin_amdgcn_mfma_f32_16x16x32_bf16(ra1, at1, uu, 0, 0, 0);
#pragma unroll
                for (int r = 0; r < 4; r++) {
                    const int row = sj * 16 + quad * 4 + r;
                    UTp[row * 72 + tW] = f2bf_h(uu[r]);
                    UTk[row * 72 + tW] = f2bf_h(ksc_l * uu[r]);
                }
            }
        }
        block_barrier();   // B3

        {
#pragma unroll
            for (int i = 0; i < 2; i++)
#pragma unroll
                for (int j = 0; j < 4; j++) Sacc[i][j] *= gL;
            const u16* KTp = KT + wq * 4616;
#pragma unroll
            for (int k0 = 0; k0 < 64; k0 += 32) {
                bf16x8 au[2], bk[4];
#pragma unroll
                for (int i = 0; i < 2; i++) au[i] = ldfrag(UTk, 72, isQ * 32 + i * 16, k0, lane);
#pragma unroll
                for (int j = 0; j < 4; j++)
                    bk[j] = *(const bf16x8*)(KTp + (size_t)(j * 16 + l15) * 72 +
                                             ((k0 + quad * 8 + toff[j]) & 63));
#pragma unroll
                for (int i = 0; i < 2; i++)
#pragma unroll
                    for (int j = 0; j < 4; j++)
                        Sacc[i][j] = __builtin_amdgcn_mfma_f32_16x16x32_bf16(au[i], bk[j], Sacc[i][j], 0, 0, 0);
            }
#pragma unroll
            for (int i = 0; i < 2; i++)
#pragma unroll
                for (int j = 0; j < 4; j++)
#pragma unroll
                    for (int r = 0; r < 4; r++)
                        ST[(isQ * 32 + i * 16 + quad * 4 + r) * 264 + wq * 64 + j * 16 + l15] = f2bf_h(Sacc[i][j][r]);
        }
        block_barrier();   // B4
    };

#pragma unroll 1
    for (int c = 0; c < 64; c += 2) {
        body(F0, F1, c);
        body(F1, F0, c + 1);
    }

    if (isQ) {
#pragma unroll
        for (int sj = 0; sj < 4; sj++) {
            bf16x8 ua0 = ldfrag(UTp, 72, sj * 16, 0, lane);
            oaccP[sj] = __builtin_amdgcn_mfma_f32_16x16x32_bf16(ua0, amP0, oaccP[sj], 0, 0, 0);
            bf16x8 ua1 = ldfrag(UTp, 72, sj * 16, 32, lane);
            oaccP[sj] = __builtin_amdgcn_mfma_f32_16x16x32_bf16(ua1, amP1, oaccP[sj], 0, 0, 0);
        }
#pragma unroll
        for (int sj = 0; sj < 4; sj++) {
            u16x4 o4;
#pragma unroll
            for (int r = 0; r < 4; r++) o4[r] = f2bf_h(oaccP[sj][r]);
            *(u16x4*)(Ob + obP + sj * 16 + quad * 4) = o4;
        }
    }
}

// ---------------------------------------------------------------------------
// Gated RMSNorm + SiLU; 1 row (4 heads) per 1024-thread block.
// ---------------------------------------------------------------------------
__global__ __launch_bounds__(1024) void gate_norm_kernel(const u16* __restrict__ O,
                                                         u16* __restrict__ G,
                                                         const float* __restrict__ norm_w) {
    const long row = blockIdx.x;
    const int c = threadIdx.x;
    const int h = c >> 8;
    const int dv = c & 255;
    const long idx = row * 1024 + c;
    float o = bf2f(O[idx]);
    float s = o * o;
#pragma unroll
    for (int off = 32; off; off >>= 1) s += __shfl_xor(s, off, 64);
    __shared__ float wsum[16];
    if ((c & 63) == 0) wsum[c >> 6] = s;
    __syncthreads();
    const float tot = wsum[h * 4] + wsum[h * 4 + 1] + wsum[h * 4 + 2] + wsum[h * 4 + 3];
    const float r = rsqrtf(tot * (1.f / 256.f) + 1e-5f);
    const float g = bf2f(G[idx]);
    const float val = o * r * norm_w[dv] * (g / (1.f + expf(-g)));
    G[idx] = f2bf_h(val);
}

// ---------------------------------------------------------------------------
extern "C" void kernel_launch(void* const* d_in, const int* in_sizes, int n_in,
                              void* d_out, int out_size, void* d_ws, size_t ws_size,
                              hipStream_t stream) {
    const float* x       = (const float*)d_in[0];
    const float* Wq      = (const float*)d_in[1];
    const float* Wk      = (const float*)d_in[2];
    const float* Wv      = (const float*)d_in[3];
    const float* Wb      = (const float*)d_in[4];
    const float* Wa      = (const float*)d_in[5];
    const float* A_log   = (const float*)d_in[6];
    const float* dt_bias = (const float*)d_in[7];
    const float* Wg      = (const float*)d_in[8];
    const float* norm_w  = (const float*)d_in[9];
    const float* Wo      = (const float*)d_in[10];

    // workspace: ~221 MB (R7's 212 + WbaT 0.26 + preBA 8.4)
    char* p = (char*)d_ws;
    u16*   WT   = (u16*)p;   p += (size_t)5120 * 1024 * 2;   // WqT|WkT|WvT|WgT|WoT
    u16*   WbaT = (u16*)p;   p += (size_t)128 * 1024 * 2;    // Wb|Wa_hi|Wa_lo ^T (12 rows used)
    u16*   Y    = (u16*)p;   p += (size_t)16384 * 3072 * 2;  // q|k|v bf16
    u16*   G    = (u16*)p;   p += (size_t)16384 * 1024 * 2;  // T|M (prep+scan)
    u16*   XO   = (u16*)p;   p += (size_t)16384 * 1024 * 2;  // xb (early), O (scan output)
    float* beta = (float*)p; p += (size_t)16384 * 4 * 4;
    float* dec  = (float*)p; p += (size_t)16384 * 4 * 4;
    u16*   GX   = (u16*)p;   p += (size_t)16384 * 1024 * 2;  // gate, then og
    float* preBA = (float*)p; p += (size_t)16384 * 128 * 4;  // x@[Wb|Wa_hi|Wa_lo] fp32

    u16* Tg = G;                                  // 8.4 MB
    u16* Mg = G + (size_t)1024 * 4096;            // 8.4 MB
    float* sfg = (float*)WT;                      // overlays dead WqT after QKV

    // merged prologue: cvt + 5 transposes + WbaT staging
    prep0_kernel<<<21552, 256, 0, stream>>>(x, XO, Wq, Wk, Wv, Wg, Wo, WT, Wb, Wa, WbaT);

    // Y = xb @ [Wq|Wk|Wv] + preBA = xb @ [Wb|Wa_hi|Wa_lo]  (25th N-tile)
    qkv_kernel<<<dim3(25, 16384 / 128), 256, 0, stream>>>(XO, WT, WbaT, Y, preBA);

    norm_beta_kernel<<<16384, 1024, 0, stream>>>(Y, preBA, A_log, dt_bias, beta, dec);

    prep_kernel<<<1024, 256, 0, stream>>>(Y, beta, dec, Tg, Mg, sfg);

    // fused: scan (blocks 0-63) + gate GEMM x@WgT -> GX (blocks 64-575)
    scan_gate_kernel<<<576, 512, 0, stream>>>(
        Y, sfg, Tg, Mg, XO, x, WT + (size_t)3072 * 1024, GX);

    gate_norm_kernel<<<16384, 1024, 0, stream>>>(XO, GX, norm_w);

    // out = og @ Wo   (fp32 out)
    gemm_kernel<1><<<dim3(1024 / 128, 16384 / 128), 256, 0, stream>>>(
        GX, WT + (size_t)4096 * 1024, d_out, 16384, 1024, 1024, 1024);
}

// Round 9
// 796.589 us; speedup vs baseline: 1.3177x; 1.0809x over previous
//
#include <hip/hip_runtime.h>

typedef unsigned short u16;
typedef __bf16 bf16x8 __attribute__((ext_vector_type(8)));
typedef u16 u16x8 __attribute__((ext_vector_type(8)));
typedef u16 u16x4 __attribute__((ext_vector_type(4)));
typedef float f32x4 __attribute__((ext_vector_type(4)));

__device__ __forceinline__ float bf2f(u16 v) {
    union { unsigned u; float f; } c; c.u = ((unsigned)v) << 16; return c.f;
}
// HW RNE f32->bf16 (single v_cvt)
__device__ __forceinline__ u16 f2bf_h(float f) {
    __bf16 h = (__bf16)f;
    union { __bf16 h; u16 u; } c; c.h = h; return c.u;
}

// MFMA fragment load (works for LDS or global pointers): LEFT operand from
// [m][k] row-major, or RIGHT operand from [n][k] row-major.
__device__ __forceinline__ bf16x8 ldfrag(const u16* base, int stride, int row0, int k0, int lane) {
    return *(const bf16x8*)(base + (size_t)(row0 + (lane & 15)) * stride + k0 + (lane >> 4) * 8);
}

// Raw workgroup barrier: commits LDS (lgkmcnt only) but does NOT drain vmcnt.
__device__ __forceinline__ void block_barrier() {
    __builtin_amdgcn_sched_barrier(0);
    asm volatile("s_waitcnt lgkmcnt(0)");
    __builtin_amdgcn_s_barrier();
    __builtin_amdgcn_sched_barrier(0);
}

// async global->LDS, 16 B per lane. LDS dest must be wave-uniform base.
__device__ __forceinline__ void gl2lds16(const void* g, void* l) {
    __builtin_amdgcn_global_load_lds(
        (const __attribute__((address_space(1))) unsigned int*)g,
        (__attribute__((address_space(3))) unsigned int*)l, 16, 0, 0);
}

// ---------------------------------------------------------------------------
// Merged prologue -- cvt (x->bf16) + 5 weight transposes + WbaT staging.
// WbaT rows: 0-3 = Wb^T, 4-7 = (bf16 hi of Wa)^T, 8-11 = (lo residual)^T.
// ---------------------------------------------------------------------------
__global__ __launch_bounds__(256) void prep0_kernel(
    const float* __restrict__ x, u16* __restrict__ XO,
    const float* __restrict__ Wq, const float* __restrict__ Wk,
    const float* __restrict__ Wv, const float* __restrict__ Wg,
    const float* __restrict__ Wo, u16* __restrict__ WT,
    const float* __restrict__ Wb, const float* __restrict__ Wa,
    u16* __restrict__ WbaT) {
    __shared__ float tile[32][33];
    const int bx = blockIdx.x, tid = threadIdx.x;

    if (bx < 16384) {                       // ---- cvt path ----
        const long i = ((long)bx * 256 + tid) * 4;
        f32x4 v = *(const f32x4*)(x + i);
        u16x4 o;
#pragma unroll
        for (int r = 0; r < 4; r++) o[r] = f2bf_h(v[r]);
        *(u16x4*)(XO + i) = o;
        return;
    }
    if (bx < 21504) {                       // ---- transpose path ----
        const int t = bx - 16384;
        const int z = t >> 10, r = t & 1023;
        const float* src = (z == 0) ? Wq : (z == 1) ? Wk : (z == 2) ? Wv : (z == 3) ? Wg : Wo;
        u16* dst = WT + (size_t)z * 1024 * 1024;
        const int n0 = (r & 31) * 32, k0 = (r >> 5) * 32;
        const int tx = tid & 31, ty = tid >> 5;
#pragma unroll
        for (int i = 0; i < 32; i += 8)
            tile[ty + i][tx] = src[(long)(k0 + ty + i) * 1024 + n0 + tx];
        __syncthreads();
#pragma unroll
        for (int i = 0; i < 32; i += 8)
            dst[(long)(n0 + ty + i) * 1024 + k0 + tx] = f2bf_h(tile[tx][ty + i]);
        return;
    }
    // ---- WbaT path: 12 x 1024 elems ----
    const int t = (bx - 21504) * 256 + tid;  // 0..12287
    const int n = t >> 10, k = t & 1023;
    float v;
    if (n < 4)      v = Wb[k * 4 + n];
    else if (n < 8) v = Wa[k * 4 + (n - 4)];
    else { float w = Wa[k * 4 + (n - 8)]; v = w - bf2f(f2bf_h(w)); }
    WbaT[(size_t)n * 1024 + k] = f2bf_h(v);
}

// ---------------------------------------------------------------------------
// QKV GEMM + preBA tile: grid (25, 128). Tiles 0-23: Y = xb @ [Wq|Wk|Wv]
// (bf16 out, RAW q/k -- prep normalizes in place). Tile 24: preBA (fp32).
// ---------------------------------------------------------------------------
__global__ __launch_bounds__(256) void qkv_kernel(const u16* __restrict__ A,
                                                  const u16* __restrict__ WTb,
                                                  const u16* __restrict__ WbaT,
                                                  u16* __restrict__ Y,
                                                  float* __restrict__ preBA) {
    __shared__ __attribute__((aligned(16))) u16 As[128][32];
    __shared__ __attribute__((aligned(16))) u16 Bs[128][32];
    const int tid  = threadIdx.x;
    const int lane = tid & 63;
    const int wave = tid >> 6;
    const int wm   = (wave >> 1) * 64;
    const int wn   = (wave & 1) * 64;
    const int isBA = (blockIdx.x == 24);
    const long m0  = (long)blockIdx.y * 128;
    const long n0  = isBA ? 0 : (long)blockIdx.x * 128;
    const u16* BT  = isBA ? WbaT : WTb;
    const int K = 1024;

    const f32x4 zero = {0.f, 0.f, 0.f, 0.f};
    f32x4 acc[4][4];
#pragma unroll
    for (int i = 0; i < 4; i++)
#pragma unroll
        for (int j = 0; j < 4; j++) acc[i][j] = zero;

    const int r0 = tid >> 2;
    const int c0 = (tid & 3) * 8;
    const u16* Ag = A + (m0 + r0) * K + c0;
    const u16* Bg = BT + (n0 + r0) * K + c0;
    u16* AsW  = &As[wave * 16][0];
    u16* AsW2 = &As[wave * 16 + 64][0];
    u16* BsW  = &Bs[wave * 16][0];
    u16* BsW2 = &Bs[wave * 16 + 64][0];

    for (int k0 = 0; k0 < K; k0 += 32) {
        gl2lds16(Ag + k0, AsW);
        gl2lds16(Ag + (long)64 * K + k0, AsW2);
        gl2lds16(Bg + k0, BsW);
        gl2lds16(Bg + (long)64 * K + k0, BsW2);
        __syncthreads();
        const int qk = (lane >> 4) * 8;
        const int mr = lane & 15;
        bf16x8 af[4], bfr[4];
#pragma unroll
        for (int i = 0; i < 4; i++) af[i]  = *(const bf16x8*)(&As[wm + i * 16 + mr][qk]);
#pragma unroll
        for (int j = 0; j < 4; j++) bfr[j] = *(const bf16x8*)(&Bs[wn + j * 16 + mr][qk]);
#pragma unroll
        for (int i = 0; i < 4; i++)
#pragma unroll
            for (int j = 0; j < 4; j++)
                acc[i][j] = __builtin_amdgcn_mfma_f32_16x16x32_bf16(af[i], bfr[j], acc[i][j], 0, 0, 0);
        __syncthreads();
    }

    const int cr = (lane >> 4) * 4;
    const int cc = lane & 15;
#pragma unroll
    for (int i = 0; i < 4; i++) {
#pragma unroll
        for (int j = 0; j < 4; j++) {
            const long m = m0 + wm + i * 16 + cr;
            const long n = n0 + wn + j * 16 + cc;
            if (isBA) {
#pragma unroll
                for (int r = 0; r < 4; r++) preBA[(m + r) * 128 + n] = acc[i][j][r];
            } else {
#pragma unroll
                for (int r = 0; r < 4; r++) Y[(m + r) * 3072 + n] = f2bf_h(acc[i][j][r]);
            }
        }
    }
}

// ---------------------------------------------------------------------------
// MFMA GEMM (bf16 A/B, gll staging) -- used for the out GEMM.
// ---------------------------------------------------------------------------
template <int F32OUT>
__global__ __launch_bounds__(256) void gemm_kernel(const u16* __restrict__ A,
                                                   const u16* __restrict__ BT,
                                                   void* __restrict__ Cv,
                                                   int M, int N, int K, int ldc) {
    __shared__ __attribute__((aligned(16))) u16 As[128][32];
    __shared__ __attribute__((aligned(16))) u16 Bs[128][32];
    const int tid  = threadIdx.x;
    const int lane = tid & 63;
    const int wave = tid >> 6;
    const int wm   = (wave >> 1) * 64;
    const int wn   = (wave & 1) * 64;
    const long m0  = (long)blockIdx.y * 128;
    const long n0  = (long)blockIdx.x * 128;

    const f32x4 zero = {0.f, 0.f, 0.f, 0.f};
    f32x4 acc[4][4];
#pragma unroll
    for (int i = 0; i < 4; i++)
#pragma unroll
        for (int j = 0; j < 4; j++) acc[i][j] = zero;

    const int r0 = tid >> 2;
    const int c0 = (tid & 3) * 8;
    const u16* Ag = A + (m0 + r0) * K + c0;
    const u16* Bg = BT + (n0 + r0) * K + c0;
    u16* AsW  = &As[wave * 16][0];
    u16* AsW2 = &As[wave * 16 + 64][0];
    u16* BsW  = &Bs[wave * 16][0];
    u16* BsW2 = &Bs[wave * 16 + 64][0];

    for (int k0 = 0; k0 < K; k0 += 32) {
        gl2lds16(Ag + k0, AsW);
        gl2lds16(Ag + (long)64 * K + k0, AsW2);
        gl2lds16(Bg + k0, BsW);
        gl2lds16(Bg + (long)64 * K + k0, BsW2);
        __syncthreads();
        const int qk = (lane >> 4) * 8;
        const int mr = lane & 15;
        bf16x8 af[4], bfr[4];
#pragma unroll
        for (int i = 0; i < 4; i++) af[i]  = *(const bf16x8*)(&As[wm + i * 16 + mr][qk]);
#pragma unroll
        for (int j = 0; j < 4; j++) bfr[j] = *(const bf16x8*)(&Bs[wn + j * 16 + mr][qk]);
#pragma unroll
        for (int i = 0; i < 4; i++)
#pragma unroll
            for (int j = 0; j < 4; j++)
                acc[i][j] = __builtin_amdgcn_mfma_f32_16x16x32_bf16(af[i], bfr[j], acc[i][j], 0, 0, 0);
        __syncthreads();
    }

    const int cr = (lane >> 4) * 4;
    const int cc = lane & 15;
#pragma unroll
    for (int i = 0; i < 4; i++) {
#pragma unroll
        for (int j = 0; j < 4; j++) {
            const long m = m0 + wm + i * 16 + cr;
            const long n = n0 + wn + j * 16 + cc;
            if (F32OUT) {
                float* C = (float*)Cv;
#pragma unroll
                for (int r = 0; r < 4; r++) C[(m + r) * ldc + n] = acc[i][j][r];
            } else {
                u16* C = (u16*)Cv;
#pragma unroll
                for (int r = 0; r < 4; r++) C[(m + r) * ldc + n] = f2bf_h(acc[i][j][r]);
            }
        }
    }
}

// ---------------------------------------------------------------------------
// PASS A (chunk-parallel prep), R9: norm_beta FUSED IN.
//  - stages RAW q/k, accumulates per-row sumsq during staging,
//    reduces across seg-lanes (shfl_xor 1,2), normalizes in LDS AND
//    writes normalized q/k back to Y (scan reads Y).
//  - beta/dec computed inline in wave 0 from preBA (no global buffers).
// ---------------------------------------------------------------------------
__global__ __launch_bounds__(256) void prep_kernel(u16* __restrict__ Y,
                                                   const float* __restrict__ preBA,
                                                   const float* __restrict__ A_log,
                                                   const float* __restrict__ dt_bias,
                                                   u16* __restrict__ Tg,
                                                   u16* __restrict__ Mg,
                                                   float* __restrict__ sfg) {
    __shared__ __attribute__((aligned(16))) u16 lds[38400];
    __shared__ float sf[320];
    u16* KS  = lds;            // 64 x 264
    u16* QS  = lds + 16896;    // 64 x 264
    u16* AM  = lds + 33792;    // 64 x 72
    u16* Tm  = lds;            // overlays after G phase
    u16* AMT = lds + 4608;
    u16* MP  = lds + 9216;
    u16* MPT = lds + 13824;

    const int bx = blockIdx.x;
    const int bh = bx >> 6, c = bx & 63;
    const int b = bh >> 2, h = bh & 3;
    const int tid = threadIdx.x, lane = tid & 63, wv = tid >> 6;
    const int quad = lane >> 4, l15 = lane & 15;
    const int tld = tid >> 2, seg = tid & 3;
    const long bt0 = (long)b * 4096 + c * 64;
    u16* Tc = Tg + (size_t)(bh * 64 + c) * 4096;
    u16* Mc = Mg + (size_t)(bh * 64 + c) * 4096;
    const f32x4 z4 = {0.f, 0.f, 0.f, 0.f};

    // ---- stage RAW K,Q + per-row sumsq ----
    float kss = 0.f, qss = 0.f;
    {
        const long rb = (bt0 + tld) * 3072 + h * 256 + seg * 64;
#pragma unroll
        for (int i = 0; i < 8; i++) {
            u16x8 kv8 = *(const u16x8*)&Y[rb + 1024 + i * 8];
            u16x8 qv8 = *(const u16x8*)&Y[rb + i * 8];
            *(u16x8*)&KS[tld * 264 + seg * 64 + i * 8] = kv8;
            *(u16x8*)&QS[tld * 264 + seg * 64 + i * 8] = qv8;
#pragma unroll
            for (int r = 0; r < 8; r++) {
                const float kf = bf2f(kv8[r]), qf = bf2f(qv8[r]);
                kss += kf * kf; qss += qf * qf;
            }
        }
    }
    // reduce over the 4 seg-lanes of this row (lanes differing in bits 0-1)
    kss += __shfl_xor(kss, 1, 64); kss += __shfl_xor(kss, 2, 64);
    qss += __shfl_xor(qss, 1, 64); qss += __shfl_xor(qss, 2, 64);
    const float skk = rsqrtf(kss + 1e-6f);
    const float sqq = rsqrtf(qss + 1e-6f) * 0.0625f;
    // normalize in LDS + write back to Y (scan consumes normalized q/k)
    {
        const long rb = (bt0 + tld) * 3072 + h * 256 + seg * 64;
#pragma unroll
        for (int i = 0; i < 8; i++) {
            u16x8 kv8 = *(u16x8*)&KS[tld * 264 + seg * 64 + i * 8];
            u16x8 qv8 = *(u16x8*)&QS[tld * 264 + seg * 64 + i * 8];
#pragma unroll
            for (int r = 0; r < 8; r++) {
                kv8[r] = f2bf_h(skk * bf2f(kv8[r]));
                qv8[r] = f2bf_h(sqq * bf2f(qv8[r]));
            }
            *(u16x8*)&KS[tld * 264 + seg * 64 + i * 8] = kv8;
            *(u16x8*)&QS[tld * 264 + seg * 64 + i * 8] = qv8;
            *(u16x8*)&Y[rb + 1024 + i * 8] = kv8;
            *(u16x8*)&Y[rb + i * 8]        = qv8;
        }
    }
    if (wv == 0) {
        // beta/dec inline from preBA (Wa split hi+lo for fp32-equiv dec)
        const float* pb = preBA + (size_t)(bt0 + lane) * 128;
        const float bt_ = 1.f / (1.f + expf(-pb[h]));
        const float z = pb[4 + h] + pb[8 + h] + dt_bias[h];
        const float sp = (z > 0.f) ? (z + log1pf(expf(-z))) : log1pf(expf(z));
        float lg = -expf(A_log[h]) * sp * 1.44269504f;   // log2(dec)
        lg = fmaxf(lg, -99.6578f);                        // dec >= ~1e-30 guard
#pragma unroll
        for (int off = 1; off < 64; off <<= 1) {
            float o = __shfl_up(lg, off, 64);
            if (lane >= off) lg += o;
        }
        sf[lane] = lg; sf[192 + lane] = bt_;
        float lgL = __shfl(lg, 63, 64);
        float g = exp2f(lg);
        float* sfc = sfg + (size_t)(bh * 64 + c) * 256;
        sfc[lane]       = g;
        sfc[64 + lane]  = bt_ * g;
        sfc[128 + lane] = bt_;
        sfc[192 + lane] = exp2f(lgL - lg);
    }
    __syncthreads();   // B1

    {
        const u16* Ab = (wv < 2) ? KS : QS;
        const int mb = (wv & 1) * 32;
        f32x4 g[2][4];
#pragma unroll
        for (int mi = 0; mi < 2; mi++)
#pragma unroll
            for (int sj = 0; sj < 4; sj++) g[mi][sj] = z4;
#pragma unroll 2
        for (int k0 = 0; k0 < 256; k0 += 32) {
            bf16x8 bfr[4];
#pragma unroll
            for (int sj = 0; sj < 4; sj++) bfr[sj] = ldfrag(KS, 264, sj * 16, k0, lane);
#pragma unroll
            for (int mi = 0; mi < 2; mi++) {
                bf16x8 af = ldfrag(Ab, 264, mb + mi * 16, k0, lane);
#pragma unroll
                for (int sj = 0; sj < 4; sj++)
                    g[mi][sj] = __builtin_amdgcn_mfma_f32_16x16x32_bf16(af, bfr[sj], g[mi][sj], 0, 0, 0);
            }
        }
#pragma unroll
        for (int mi = 0; mi < 2; mi++)
#pragma unroll
            for (int sj = 0; sj < 4; sj++)
#pragma unroll
                for (int r = 0; r < 4; r++) {
                    const int t_ = mb + mi * 16 + quad * 4 + r, s_ = sj * 16 + l15;
                    if (wv < 2)
                        AM[t_ * 72 + s_] = (s_ < t_) ? f2bf_h(sf[192 + t_] * exp2f(sf[t_] - sf[s_]) * g[mi][sj][r]) : (u16)0;
                    else
                        Mc[t_ * 64 + s_] = (s_ <= t_) ? f2bf_h(exp2f(sf[t_] - sf[s_]) * g[mi][sj][r]) : (u16)0;
                }
    }
    __syncthreads();   // B2

    {
        const int t_ = tid >> 2;
#pragma unroll
        for (int i = 0; i < 16; i++) {
            const int s_ = (tid & 3) * 16 + i;
            const u16 a = AM[t_ * 72 + s_];
            Tm[t_ * 72 + s_] = (t_ == s_) ? (u16)0x3F80 : (u16)(a ^ 0x8000);
            AMT[s_ * 72 + t_] = a;
        }
    }
    __syncthreads();   // B3

    {
        f32x4 sq[4];
#pragma unroll
        for (int sj = 0; sj < 4; sj++) sq[sj] = z4;
#pragma unroll
        for (int k0 = 0; k0 < 64; k0 += 32) {
            bf16x8 a = ldfrag(AM, 72, 16 * wv, k0, lane);
#pragma unroll
            for (int sj = 0; sj < 4; sj++) {
                bf16x8 bb = ldfrag(AMT, 72, sj * 16, k0, lane);
                sq[sj] = __builtin_amdgcn_mfma_f32_16x16x32_bf16(a, bb, sq[sj], 0, 0, 0);
            }
        }
#pragma unroll
        for (int sj = 0; sj < 4; sj++)
#pragma unroll
            for (int r = 0; r < 4; r++) {
                const int t_ = 16 * wv + quad * 4 + r, s_ = sj * 16 + l15;
                const u16 vbf = f2bf_h(sq[sj][r]);
                MP[t_ * 72 + s_] = vbf;
                MPT[s_ * 72 + t_] = vbf;
            }
        __syncthreads();   // B4
    }

#pragma unroll 1
    for (int jj = 0; jj < 5; jj++) {
        const bool last = (jj == 4);
        f32x4 pp[4], sq[4];
#pragma unroll
        for (int sj = 0; sj < 4; sj++) {
            sq[sj] = z4;
#pragma unroll
            for (int r = 0; r < 4; r++)
                pp[sj][r] = bf2f(Tm[(16 * wv + quad * 4 + r) * 72 + sj * 16 + l15]);
        }
#pragma unroll
        for (int k0 = 0; k0 < 64; k0 += 32) {
            bf16x8 at = ldfrag(Tm, 72, 16 * wv, k0, lane);
            bf16x8 am = ldfrag(MP, 72, 16 * wv, k0, lane);
#pragma unroll
            for (int sj = 0; sj < 4; sj++) {
                bf16x8 bb = ldfrag(MPT, 72, sj * 16, k0, lane);
                pp[sj] = __builtin_amdgcn_mfma_f32_16x16x32_bf16(at, bb, pp[sj], 0, 0, 0);
                if (!last) sq[sj] = __builtin_amdgcn_mfma_f32_16x16x32_bf16(am, bb, sq[sj], 0, 0, 0);
            }
        }
        __syncthreads();
#pragma unroll
        for (int sj = 0; sj < 4; sj++)
#pragma unroll
            for (int r = 0; r < 4; r++) {
                const int t_ = 16 * wv + quad * 4 + r, s_ = sj * 16 + l15;
                Tm[t_ * 72 + s_] = f2bf_h(pp[sj][r]);
                if (!last) {
                    const u16 vbf = f2bf_h(sq[sj][r]);
                    MP[t_ * 72 + s_] = vbf;
                    MPT[s_ * 72 + t_] = vbf;
                }
            }
        __syncthreads();
    }

    {
        const int t_ = tid >> 2;
#pragma unroll
        for (int i = 0; i < 16; i++) {
            const int s_ = (tid & 3) * 16 + i;
            Tc[t_ * 64 + s_] = Tm[t_ * 72 + s_];
        }
    }
}

// ---------------------------------------------------------------------------
// PASS B fused with the gate GEMM. Unchanged from R7/R8 (verified winner).
// ---------------------------------------------------------------------------
struct Frag { bf16x8 f[8]; };
#define LDA 40

__global__ __launch_bounds__(512, 2) void scan_gate_kernel(
    const u16* __restrict__ Y, const float* __restrict__ sfg,
    const u16* __restrict__ Tg, const u16* __restrict__ Mg,
    u16* __restrict__ Ob,
    const float* __restrict__ x, const u16* __restrict__ WgT,
    u16* __restrict__ GX) {
    __shared__ __attribute__((aligned(16))) u16 smem[49184];

    const int tid = threadIdx.x;

    if (blockIdx.x >= 64) {
        // ================= gate GEMM path: two 128^2 tiles =================
        u16* As = smem + (tid >> 8) * 9216;            // [128][LDA=40]
        u16* Bs = As + 5120;                            // [128][32]
        const int t256 = tid & 255;
        const int lane = t256 & 63;
        const int wave = t256 >> 6;
        const int wm   = (wave >> 1) * 64;
        const int wn   = (wave & 1) * 64;
        const int tl   = (blockIdx.x - 64) * 2 + (tid >> 8);   // 0..1023
        const long m0  = (long)(tl >> 3) * 128;
        const long n0  = (long)(tl & 7) * 128;
        const int K = 1024, ldc = 1024;

        const f32x4 zero = {0.f, 0.f, 0.f, 0.f};
        f32x4 acc[4][4];
#pragma unroll
        for (int i = 0; i < 4; i++)
#pragma unroll
            for (int j = 0; j < 4; j++) acc[i][j] = zero;

        const int r0 = t256 >> 2;
        const int c0 = (t256 & 3) * 8;
        const float* Ag = x + (m0 + r0) * K + c0;
        const u16* Bg = WgT + (n0 + r0) * K + c0;
        u16* BsW  = Bs + wave * 16 * 32;
        u16* BsW2 = Bs + (wave * 16 + 64) * 32;

        for (int k0 = 0; k0 < K; k0 += 32) {
            gl2lds16(Bg + k0, BsW);
            gl2lds16(Bg + (long)64 * K + k0, BsW2);
            f32x4 af0 = *(const f32x4*)(Ag + k0);
            f32x4 af1 = *(const f32x4*)(Ag + k0 + 4);
            f32x4 ag0 = *(const f32x4*)(Ag + (long)64 * K + k0);
            f32x4 ag1 = *(const f32x4*)(Ag + (long)64 * K + k0 + 4);
            u16x8 a0, a1;
#pragma unroll
            for (int r = 0; r < 4; r++) {
                a0[r] = f2bf_h(af0[r]); a0[r + 4] = f2bf_h(af1[r]);
                a1[r] = f2bf_h(ag0[r]); a1[r + 4] = f2bf_h(ag1[r]);
            }
            *(u16x8*)(As + r0 * LDA + c0)        = a0;
            *(u16x8*)(As + (r0 + 64) * LDA + c0) = a1;
            __syncthreads();
            const int qk = (lane >> 4) * 8;
            const int mr = lane & 15;
            bf16x8 af[4], bfr[4];
#pragma unroll
            for (int i = 0; i < 4; i++) af[i]  = *(const bf16x8*)(As + (wm + i * 16 + mr) * LDA + qk);
#pragma unroll
            for (int j = 0; j < 4; j++) bfr[j] = *(const bf16x8*)(Bs + (wn + j * 16 + mr) * 32 + qk);
#pragma unroll
            for (int i = 0; i < 4; i++)
#pragma unroll
                for (int j = 0; j < 4; j++)
                    acc[i][j] = __builtin_amdgcn_mfma_f32_16x16x32_bf16(af[i], bfr[j], acc[i][j], 0, 0, 0);
            __syncthreads();
        }

        const int cr = (lane >> 4) * 4;
        const int cc = lane & 15;
#pragma unroll
        for (int i = 0; i < 4; i++) {
#pragma unroll
            for (int j = 0; j < 4; j++) {
                const long m = m0 + wm + i * 16 + cr;
                const long n = n0 + wn + j * 16 + cc;
#pragma unroll
                for (int r = 0; r < 4; r++) GX[(m + r) * ldc + n] = f2bf_h(acc[i][j][r]);
            }
        }
        return;
    }

    // ====================== scan path (unchanged) ======================
    u16* KT   = smem;              // 4*4616
    u16* ST   = smem + 18464;      // 64*264
    u16* RHST = smem + 35360;      // 64*72
    u16* UTp  = smem + 39968;      // 64*72
    u16* UTk  = smem + 44576;      // 64*72

    const int px = blockIdx.x;
    const int bh = (px & 7) | ((px >> 5) << 3);
    const int dvs = (px >> 3) & 3;
    const int b = bh >> 2, h = bh & 3;
    const int lane = tid & 63, wv = tid >> 6;
    const int wq = wv & 3;
    const int isQ = wv >> 2;
    const int quad = lane >> 4, l15 = lane & 15;
    const int tW = 16 * wq + l15;
    const int tph = 16 * ((wq + quad) & 3) + l15;
    int toff[4];
#pragma unroll
    for (int j = 0; j < 4; j++) toff[j] = ((((j << 1) + (l15 >> 3)) & 3) << 4);
    const f32x4 z4 = {0.f, 0.f, 0.f, 0.f};

    f32x4 Sacc[2][4];
#pragma unroll
    for (int i = 0; i < 2; i++)
#pragma unroll
        for (int j = 0; j < 4; j++) Sacc[i][j] = z4;
    for (int i = tid; i < 64 * 264; i += 512) ST[i] = 0;
    __syncthreads();

    const long roleOff = isQ ? 0 : 1024;
    Frag F0, F1;
    {
        const u16* Pg = Y + ((long)b * 4096) * 3072 + roleOff + h * 256;
#pragma unroll
        for (int i = 0; i < 8; i++) F0.f[i] = ldfrag(Pg, 3072, 16 * wq, i * 32, lane);
    }

    f32x4 oaccP[4];
#pragma unroll
    for (int j = 0; j < 4; j++) oaccP[j] = z4;
    bf16x8 amP0 = {}, amP1 = {};
    long obP = 0;
    int havePrev = 0;

    auto body = [&](Frag& cur, Frag& nxt, int c) {
        const long bt0 = (long)b * 4096 + (long)c * 64;
        const int cn = (c < 63) ? c + 1 : 63;

        {
            const u16* Pg = Y + ((long)b * 4096 + (long)cn * 64) * 3072 + roleOff + h * 256;
#pragma unroll
            for (int i = 0; i < 8; i++) nxt.f[i] = ldfrag(Pg, 3072, 16 * wq, i * 32, lane);
        }

        const u16* Tc = Tg + (size_t)(bh * 64 + c) * 4096;
        bf16x8 at0 = ldfrag(Tc, 64, 16 * wq, 0, lane);
        bf16x8 at1 = ldfrag(Tc, 64, 16 * wq, 32, lane);
        const float* sfc = sfg + (size_t)(bh * 64 + c) * 256;
        const float gam_l = sfc[tW];
        const float bg_l  = sfc[64 + tW];
        const float bet_l = sfc[128 + tW];
        const float ksc_l = sfc[192 + tW];
        const float gL    = sfc[63];

        u16x4 v4[4];
        if (!isQ) {
            const u16* Vr = Y + (bt0 + tW) * 3072 + 2048 + h * 256 + dvs * 64;
#pragma unroll
            for (int j = 0; j < 4; j++) v4[j] = *(const u16x4*)(Vr + j * 16 + quad * 4);
        } else {
            const u16* Mc = Mg + (size_t)(bh * 64 + c) * 4096;
            bf16x8 amN0 = ldfrag(Mc, 64, 16 * wq, 0, lane);
            bf16x8 amN1 = ldfrag(Mc, 64, 16 * wq, 32, lane);
            if (havePrev) {
#pragma unroll
                for (int sj = 0; sj < 4; sj++) {
                    bf16x8 ua0 = ldfrag(UTp, 72, sj * 16, 0, lane);
                    oaccP[sj] = __builtin_amdgcn_mfma_f32_16x16x32_bf16(ua0, amP0, oaccP[sj], 0, 0, 0);
                    bf16x8 ua1 = ldfrag(UTp, 72, sj * 16, 32, lane);
                    oaccP[sj] = __builtin_amdgcn_mfma_f32_16x16x32_bf16(ua1, amP1, oaccP[sj], 0, 0, 0);
                }
#pragma unroll
                for (int sj = 0; sj < 4; sj++) {
                    u16x4 o4;
#pragma unroll
                    for (int r = 0; r < 4; r++) o4[r] = f2bf_h(oaccP[sj][r]);
                    *(u16x4*)(Ob + obP + sj * 16 + quad * 4) = o4;
                }
            }
            amP0 = amN0; amP1 = amN1;
        }

        f32x4 p[4];
#pragma unroll
        for (int j = 0; j < 4; j++) p[j] = z4;
#pragma unroll
        for (int i = 0; i < 8; i++) {
            bf16x8 sfr[4];
#pragma unroll
            for (int j = 0; j < 4; j++) sfr[j] = ldfrag(ST, 264, j * 16, i * 32, lane);
#pragma unroll
            for (int j = 0; j < 4; j++)
                p[j] = __builtin_amdgcn_mfma_f32_16x16x32_bf16(sfr[j], cur.f[i], p[j], 0, 0, 0);
        }

        if (!isQ) {
#pragma unroll
            for (int i = 0; i < 8; i++) {
                const u16* src = (const u16*)&cur.f[i];
                u16* dst = KT + (i >> 1) * 4616 + ((i & 1) * 32 + quad * 8) * 72 + tph;
#pragma unroll
                for (int jj = 0; jj < 8; jj++) dst[jj * 72] = src[jj];
            }
#pragma unroll
            for (int j = 0; j < 4; j++)
#pragma unroll
                for (int r = 0; r < 4; r++) {
                    const int row = j * 16 + quad * 4 + r;
                    RHST[row * 72 + tW] = f2bf_h(bet_l * bf2f(v4[j][r]) - bg_l * p[j][r]);
                }
        } else {
#pragma unroll
            for (int j = 0; j < 4; j++)
#pragma unroll
                for (int r = 0; r < 4; r++) oaccP[j][r] = gam_l * p[j][r];
            obP = (bt0 + tW) * 1024 + h * 256 + (long)dvs * 64;
            havePrev = 1;
        }
        block_barrier();   // B2

        {
#pragma unroll
            for (int s2 = 0; s2 < 2; s2++) {
                const int sj = isQ * 2 + s2;
                f32x4 uu = z4;
                bf16x8 ra0 = ldfrag(RHST, 72, sj * 16, 0, lane);
                uu = __builtin_amdgcn_mfma_f32_16x16x32_bf16(ra0, at0, uu, 0, 0, 0);
                bf16x8 ra1 = ldfrag(RHST, 72, sj * 16, 32, lane);
                uu = __builtin_amdgcn_mfma_f32_16x16x32_bf16(ra1, at1, uu, 0, 0, 0);
#pragma unroll
                for (int r = 0; r < 4; r++) {
                    const int row = sj * 16 + quad * 4 + r;
                    UTp[row * 72 + tW] = f2bf_h(uu[r]);
                    UTk[row * 72 + tW] = f2bf_h(ksc_l * uu[r]);
                }
            }
        }
        block_barrier();   // B3

        {
#pragma unroll
            for (int i = 0; i < 2; i++)
#pragma unroll
                for (int j = 0; j < 4; j++) Sacc[i][j] *= gL;
            const u16* KTp = KT + wq * 4616;
#pragma unroll
            for (int k0 = 0; k0 < 64; k0 += 32) {
                bf16x8 au[2], bk[4];
#pragma unroll
                for (int i = 0; i < 2; i++) au[i] = ldfrag(UTk, 72, isQ * 32 + i * 16, k0, lane);
#pragma unroll
                for (int j = 0; j < 4; j++)
                    bk[j] = *(const bf16x8*)(KTp + (size_t)(j * 16 + l15) * 72 +
                                             ((k0 + quad * 8 + toff[j]) & 63));
#pragma unroll
                for (int i = 0; i < 2; i++)
#pragma unroll
                    for (int j = 0; j < 4; j++)
                        Sacc[i][j] = __builtin_amdgcn_mfma_f32_16x16x32_bf16(au[i], bk[j], Sacc[i][j], 0, 0, 0);
            }
#pragma unroll
            for (int i = 0; i < 2; i++)
#pragma unroll
                for (int j = 0; j < 4; j++)
#pragma unroll
                    for (int r = 0; r < 4; r++)
                        ST[(isQ * 32 + i * 16 + quad * 4 + r) * 264 + wq * 64 + j * 16 + l15] = f2bf_h(Sacc[i][j][r]);
        }
        block_barrier();   // B4
    };

#pragma unroll 1
    for (int c = 0; c < 64; c += 2) {
        body(F0, F1, c);
        body(F1, F0, c + 1);
    }

    if (isQ) {
#pragma unroll
        for (int sj = 0; sj < 4; sj++) {
            bf16x8 ua0 = ldfrag(UTp, 72, sj * 16, 0, lane);
            oaccP[sj] = __builtin_amdgcn_mfma_f32_16x16x32_bf16(ua0, amP0, oaccP[sj], 0, 0, 0);
            bf16x8 ua1 = ldfrag(UTp, 72, sj * 16, 32, lane);
            oaccP[sj] = __builtin_amdgcn_mfma_f32_16x16x32_bf16(ua1, amP1, oaccP[sj], 0, 0, 0);
        }
#pragma unroll
        for (int sj = 0; sj < 4; sj++) {
            u16x4 o4;
#pragma unroll
            for (int r = 0; r < 4; r++) o4[r] = f2bf_h(oaccP[sj][r]);
            *(u16x4*)(Ob + obP + sj * 16 + quad * 4) = o4;
        }
    }
}

// ---------------------------------------------------------------------------
// Gated RMSNorm + SiLU; 1 row (4 heads) per 1024-thread block.
// ---------------------------------------------------------------------------
__global__ __launch_bounds__(1024) void gate_norm_kernel(const u16* __restrict__ O,
                                                         u16* __restrict__ G,
                                                         const float* __restrict__ norm_w) {
    const long row = blockIdx.x;
    const int c = threadIdx.x;
    const int h = c >> 8;
    const int dv = c & 255;
    const long idx = row * 1024 + c;
    float o = bf2f(O[idx]);
    float s = o * o;
#pragma unroll
    for (int off = 32; off; off >>= 1) s += __shfl_xor(s, off, 64);
    __shared__ float wsum[16];
    if ((c & 63) == 0) wsum[c >> 6] = s;
    __syncthreads();
    const float tot = wsum[h * 4] + wsum[h * 4 + 1] + wsum[h * 4 + 2] + wsum[h * 4 + 3];
    const float r = rsqrtf(tot * (1.f / 256.f) + 1e-5f);
    const float g = bf2f(G[idx]);
    const float val = o * r * norm_w[dv] * (g / (1.f + expf(-g)));
    G[idx] = f2bf_h(val);
}

// ---------------------------------------------------------------------------
extern "C" void kernel_launch(void* const* d_in, const int* in_sizes, int n_in,
                              void* d_out, int out_size, void* d_ws, size_t ws_size,
                              hipStream_t stream) {
    const float* x       = (const float*)d_in[0];
    const float* Wq      = (const float*)d_in[1];
    const float* Wk      = (const float*)d_in[2];
    const float* Wv      = (const float*)d_in[3];
    const float* Wb      = (const float*)d_in[4];
    const float* Wa      = (const float*)d_in[5];
    const float* A_log   = (const float*)d_in[6];
    const float* dt_bias = (const float*)d_in[7];
    const float* Wg      = (const float*)d_in[8];
    const float* norm_w  = (const float*)d_in[9];
    const float* Wo      = (const float*)d_in[10];

    // workspace: ~221 MB (same as R8; beta/dec buffers now dead but kept
    // in the layout budget).
    char* p = (char*)d_ws;
    u16*   WT   = (u16*)p;   p += (size_t)5120 * 1024 * 2;   // WqT|WkT|WvT|WgT|WoT
    u16*   WbaT = (u16*)p;   p += (size_t)128 * 1024 * 2;    // Wb|Wa_hi|Wa_lo ^T
    u16*   Y    = (u16*)p;   p += (size_t)16384 * 3072 * 2;  // q|k|v bf16
    u16*   G    = (u16*)p;   p += (size_t)16384 * 1024 * 2;  // T|M (prep+scan)
    u16*   XO   = (u16*)p;   p += (size_t)16384 * 1024 * 2;  // xb (early), O (scan output)
    u16*   GX   = (u16*)p;   p += (size_t)16384 * 1024 * 2;  // gate, then og
    float* preBA = (float*)p; p += (size_t)16384 * 128 * 4;  // x@[Wb|Wa_hi|Wa_lo] fp32

    u16* Tg = G;                                  // 8.4 MB
    u16* Mg = G + (size_t)1024 * 4096;            // 8.4 MB
    float* sfg = (float*)WT;                      // overlays dead WqT after QKV

    // merged prologue: cvt + 5 transposes + WbaT staging
    prep0_kernel<<<21552, 256, 0, stream>>>(x, XO, Wq, Wk, Wv, Wg, Wo, WT, Wb, Wa, WbaT);

    // Y = xb @ [Wq|Wk|Wv] (raw) + preBA = xb @ [Wb|Wa_hi|Wa_lo]
    qkv_kernel<<<dim3(25, 16384 / 128), 256, 0, stream>>>(XO, WT, WbaT, Y, preBA);

    // prep: fused norm_beta (normalizes q/k in Y + computes beta/dec inline)
    prep_kernel<<<1024, 256, 0, stream>>>(Y, preBA, A_log, dt_bias, Tg, Mg, sfg);

    // fused: scan (blocks 0-63) + gate GEMM x@WgT -> GX (blocks 64-575)
    scan_gate_kernel<<<576, 512, 0, stream>>>(
        Y, sfg, Tg, Mg, XO, x, WT + (size_t)3072 * 1024, GX);

    gate_norm_kernel<<<16384, 1024, 0, stream>>>(XO, GX, norm_w);

    // out = og @ Wo   (fp32 out)
    gemm_kernel<1><<<dim3(1024 / 128, 16384 / 128), 256, 0, stream>>>(
        GX, WT + (size_t)4096 * 1024, d_out, 16384, 1024, 1024, 1024);
}